// Round 1
// baseline (9999.070 us; speedup 1.0000x reference)
//
#include <hip/hip_runtime.h>
#include <math.h>

namespace {

constexpr int kB = 2, kS = 1024, kE = 1024, kH = 16, kD = 64, kV = 32000, kFH = 512;
constexpr int kBS = kB * kS;   // 2048 rows
constexpr int kHD = kH * kD;   // 1024

// ---------------- embedding + positional encoding ----------------
__global__ __launch_bounds__(256) void embed_pe_k(const int* __restrict__ tok,
                                                  const float* __restrict__ emb,
                                                  float* __restrict__ out) {
  int row = blockIdx.x;              // b*S + s
  int s = row & (kS - 1);
  int t = tok[row];
  const float* src = emb + (size_t)t * kE;
  float* dst = out + (size_t)row * kE;
  for (int e = threadIdx.x; e < kE; e += 256) {
    int i = e >> 1;
    float denom = powf(10000.0f, (float)(2 * i) * (1.0f / (float)kE));
    float ang = (float)s / denom;
    float pe = (e & 1) ? cosf(ang) : sinf(ang);
    dst[e] = src[e] + pe;
  }
}

// ---------------- repack [H,E,D] -> [E, H*D] ----------------
__global__ __launch_bounds__(256) void repack_w_k(const float* __restrict__ w,
                                                  float* __restrict__ out) {
  int i = blockIdx.x * 256 + threadIdx.x;   // exactly H*E*D = 1M threads
  int k = i & (kD - 1);
  int e = (i >> 6) & (kE - 1);
  int h = i >> 16;                           // E*D = 65536
  out[(size_t)e * kHD + h * kD + k] = w[i];
}

// ---------------- generic fp32 GEMM: C[M,N] = A[M,K]@B[K,N] + bias, opt ReLU --------
__global__ __launch_bounds__(256) void gemm_k(const float* __restrict__ A,
                                              const float* __restrict__ Bm,
                                              const float* __restrict__ bias,
                                              float* __restrict__ C,
                                              int M, int N, int K, int relu) {
  __shared__ float As[16][65];   // As[kk][m]
  __shared__ float Bs[16][65];   // Bs[kk][n]
  int tid = threadIdx.x;
  int bn = blockIdx.x * 64, bm = blockIdx.y * 64;
  int tc = tid & 15, tr = tid >> 4;
  int lAk = tid & 15, lAm = tid >> 4;
  int lBn = tid & 63, lBk = tid >> 6;
  float acc[4][4] = {};
  for (int k0 = 0; k0 < K; k0 += 16) {
#pragma unroll
    for (int r = 0; r < 4; ++r)
      As[lAk][lAm + 16 * r] = A[(size_t)(bm + lAm + 16 * r) * K + k0 + lAk];
#pragma unroll
    for (int r = 0; r < 4; ++r)
      Bs[lBk + 4 * r][lBn] = Bm[(size_t)(k0 + lBk + 4 * r) * N + bn + lBn];
    __syncthreads();
#pragma unroll
    for (int kk = 0; kk < 16; ++kk) {
      float a0[4], b0[4];
#pragma unroll
      for (int i = 0; i < 4; ++i) a0[i] = As[kk][tr * 4 + i];
#pragma unroll
      for (int j = 0; j < 4; ++j) b0[j] = Bs[kk][tc * 4 + j];
#pragma unroll
      for (int i = 0; i < 4; ++i)
#pragma unroll
        for (int j = 0; j < 4; ++j) acc[i][j] += a0[i] * b0[j];
    }
    __syncthreads();
  }
#pragma unroll
  for (int i = 0; i < 4; ++i) {
    size_t row = (size_t)(bm + tr * 4 + i);
#pragma unroll
    for (int j = 0; j < 4; ++j) {
      int col = bn + tc * 4 + j;
      float v2 = acc[i][j] + bias[col];
      if (relu) v2 = fmaxf(v2, 0.0f);
      C[row * N + col] = v2;
    }
  }
}

// ---------------- fused attention: one block per (b,h,query) ----------------
__global__ __launch_bounds__(256) void attn_k(const float* __restrict__ q,
                                              const float* __restrict__ k,
                                              const float* __restrict__ v,
                                              float* __restrict__ out, int causal) {
  __shared__ float qs[kD];
  __shared__ float sc[kS];
  __shared__ float rbuf[20];
  __shared__ float part[4][kD];
  int idx = blockIdx.x;
  int sq = idx & (kS - 1);
  int h = (idx >> 10) & (kH - 1);
  int b = idx >> 14;
  int tid = threadIdx.x;
  int lane = tid & 63, wid = tid >> 6;
  const size_t rs = kHD;
  const float* qrow = q + (size_t)(b * kS + sq) * rs + h * kD;
  if (tid < kD) qs[tid] = qrow[tid];
  __syncthreads();
  int smax = causal ? (sq + 1) : kS;
  const float* kbase = k + (size_t)(b * kS) * rs + h * kD;
  for (int s = tid; s < smax; s += 256) {
    const float4* kr = (const float4*)(kbase + (size_t)s * rs);
    const float4* q4 = (const float4*)qs;
    float acc = 0.0f;
#pragma unroll
    for (int i = 0; i < 16; ++i) {
      float4 kv = kr[i];
      float4 qv = q4[i];
      acc += kv.x * qv.x + kv.y * qv.y + kv.z * qv.z + kv.w * qv.w;
    }
    sc[s] = acc * 0.125f;   // 1/sqrt(64)
  }
  __syncthreads();
  // block softmax over sc[0..smax)
  float lm = -INFINITY;
  for (int s = tid; s < smax; s += 256) lm = fmaxf(lm, sc[s]);
  for (int o = 32; o > 0; o >>= 1) lm = fmaxf(lm, __shfl_down(lm, o));
  if (lane == 0) rbuf[wid] = lm;
  __syncthreads();
  if (tid == 0) rbuf[16] = fmaxf(fmaxf(rbuf[0], rbuf[1]), fmaxf(rbuf[2], rbuf[3]));
  __syncthreads();
  float M = rbuf[16];
  float ls = 0.0f;
  for (int s = tid; s < smax; s += 256) {
    float p = expf(sc[s] - M);
    sc[s] = p;
    ls += p;
  }
  for (int o = 32; o > 0; o >>= 1) ls += __shfl_down(ls, o);
  if (lane == 0) rbuf[4 + wid] = ls;
  __syncthreads();
  if (tid == 0) rbuf[17] = rbuf[4] + rbuf[5] + rbuf[6] + rbuf[7];
  __syncthreads();
  float SUM = rbuf[17];
  // output: out[d] = sum_s p[s] * v[s,d] / SUM
  int d = tid & 63, g = tid >> 6;
  float acc = 0.0f;
  const float* vbase = v + (size_t)(b * kS) * rs + h * kD + d;
  for (int s = g; s < smax; s += 4) acc += sc[s] * vbase[(size_t)s * rs];
  part[g][d] = acc;
  __syncthreads();
  if (tid < kD) {
    float o2 = (part[0][tid] + part[1][tid] + part[2][tid] + part[3][tid]) / SUM;
    out[(size_t)(b * kS + sq) * rs + h * kD + tid] = o2;
  }
}

// ---------------- residual + LayerNorm ----------------
__global__ __launch_bounds__(256) void ln_res_k(const float* __restrict__ a,
                                                const float* __restrict__ b,
                                                const float* __restrict__ gamma,
                                                const float* __restrict__ beta,
                                                float* __restrict__ out) {
  __shared__ float sh[10];
  int row = blockIdx.x;
  const float* ar = a + (size_t)row * kE;
  const float* br = b + (size_t)row * kE;
  int tid = threadIdx.x;
  float t[4], s = 0.0f, q2 = 0.0f;
#pragma unroll
  for (int i = 0; i < 4; ++i) {
    int e = tid + i * 256;
    t[i] = ar[e] + br[e];
    s += t[i];
    q2 += t[i] * t[i];
  }
  for (int o = 32; o > 0; o >>= 1) { s += __shfl_down(s, o); q2 += __shfl_down(q2, o); }
  int lane = tid & 63, wid = tid >> 6;
  if (lane == 0) { sh[wid] = s; sh[4 + wid] = q2; }
  __syncthreads();
  if (tid == 0) {
    float S2 = sh[0] + sh[1] + sh[2] + sh[3];
    float Q2 = sh[4] + sh[5] + sh[6] + sh[7];
    float mean = S2 * (1.0f / kE);
    float var = Q2 * (1.0f / kE) - mean * mean;
    sh[8] = mean;
    sh[9] = rsqrtf(var + 1e-15f);
  }
  __syncthreads();
  float mean = sh[8], inv = sh[9];
#pragma unroll
  for (int i = 0; i < 4; ++i) {
    int e = tid + i * 256;
    out[(size_t)row * kE + e] = gamma[e] * ((t[i] - mean) * inv) + beta[e];
  }
}

// ---------------- row softmax over V (in place) ----------------
__global__ __launch_bounds__(256) void softmax_rows_k(float* __restrict__ x) {
  __shared__ float sh[10];
  int row = blockIdx.x;
  float* xr = x + (size_t)row * kV;
  int tid = threadIdx.x;
  float m = -INFINITY, sum = 0.0f;
  for (int i = tid; i < kV; i += 256) {
    float v2 = xr[i];
    float nm = fmaxf(m, v2);
    sum = sum * expf(m - nm) + expf(v2 - nm);
    m = nm;
  }
  for (int o = 32; o > 0; o >>= 1) {
    float om = __shfl_down(m, o), os = __shfl_down(sum, o);
    float nm = fmaxf(m, om);
    sum = sum * expf(m - nm) + os * expf(om - nm);
    m = nm;
  }
  int lane = tid & 63, wid = tid >> 6;
  if (lane == 0) { sh[wid] = m; sh[4 + wid] = sum; }
  __syncthreads();
  if (tid == 0) {
    float M = fmaxf(fmaxf(sh[0], sh[1]), fmaxf(sh[2], sh[3]));
    float S2 = sh[4] * expf(sh[0] - M) + sh[5] * expf(sh[1] - M) +
               sh[6] * expf(sh[2] - M) + sh[7] * expf(sh[3] - M);
    sh[8] = M;
    sh[9] = 1.0f / S2;
  }
  __syncthreads();
  float M = sh[8], rcp = sh[9];
  for (int i = tid; i < kV; i += 256) xr[i] = expf(xr[i] - M) * rcp;
}

}  // namespace

extern "C" void kernel_launch(void* const* d_in, const int* in_sizes, int n_in,
                              void* d_out, int out_size, void* d_ws, size_t ws_size,
                              hipStream_t stream) {
  const int*   src    = (const int*)d_in[0];
  const int*   trg    = (const int*)d_in[1];
  const float* emb_e  = (const float*)d_in[2];
  const float* emb_d  = (const float*)d_in[3];
  const float* qkv_e  = (const float*)d_in[4];
  const float* bqkv_e = (const float*)d_in[5];
  const float* wo_e   = (const float*)d_in[6];
  const float* bo_e   = (const float*)d_in[7];
  const float* qkv_m  = (const float*)d_in[8];
  const float* bqkv_m = (const float*)d_in[9];
  const float* wo_m   = (const float*)d_in[10];
  const float* bo_m   = (const float*)d_in[11];
  const float* qkv_c  = (const float*)d_in[12];
  const float* bqkv_c = (const float*)d_in[13];
  const float* wo_c   = (const float*)d_in[14];
  const float* bo_c   = (const float*)d_in[15];
  const float* gamma  = (const float*)d_in[16];
  const float* beta   = (const float*)d_in[17];
  const float* ffw1   = (const float*)d_in[18];
  const float* ffb1   = (const float*)d_in[19];
  const float* ffw2   = (const float*)d_in[20];
  const float* ffb2   = (const float*)d_in[21];
  const float* wout   = (const float*)d_in[22];
  const float* bout   = (const float*)d_in[23];
  float* out = (float*)d_out;

  float* w = (float*)d_ws;
  const size_t R = (size_t)kBS * kE;   // 2M floats
  float* enc_x = w + 0 * R;            // later reused as n2d
  float* dec_x = w + 1 * R;            // later reused as n3d
  float* qb    = w + 2 * R;
  float* kb    = w + 3 * R;
  float* vb    = w + 4 * R;
  float* ao    = w + 5 * R;
  float* t1    = w + 6 * R;
  float* n1    = w + 7 * R;            // later reused as n1d
  float* n_enc = w + 8 * R;
  float* ffh   = w + 9 * R;            // 2048*512 (0.5R)
  float* wr    = w + 9 * R + R / 2;    // 3 × (1024*1024) repacked qkv weights

  auto gemm = [&](const float* A, const float* Bm, const float* bias, float* C,
                  int M, int N, int K, int relu) {
    dim3 g(N / 64, M / 64);
    gemm_k<<<g, dim3(256), 0, stream>>>(A, Bm, bias, C, M, N, K, relu);
  };

  auto mha = [&](const float* xq, const float* xkv, const float* qkv,
                 const float* bqkv, const float* wo, const float* bo, int causal) {
    const size_t WSZ = (size_t)kE * kHD;
    for (int p = 0; p < 3; ++p)
      repack_w_k<<<(kH * kE * kD) / 256, 256, 0, stream>>>(
          qkv + (size_t)p * kH * kE * kD, wr + (size_t)p * WSZ);
    gemm(xq,  wr,           bqkv,             qb, kBS, kHD, kE, 0);
    gemm(xkv, wr + WSZ,     bqkv + kH * kD,   kb, kBS, kHD, kE, 0);
    gemm(xkv, wr + 2 * WSZ, bqkv + 2 * kH * kD, vb, kBS, kHD, kE, 0);
    attn_k<<<kB * kH * kS, 256, 0, stream>>>(qb, kb, vb, ao, causal);
    gemm(ao, wo, bo, t1, kBS, kE, kHD, 0);
  };

  // ---------------- encoder ----------------
  embed_pe_k<<<kBS, 256, 0, stream>>>(src, emb_e, enc_x);
  mha(enc_x, enc_x, qkv_e, bqkv_e, wo_e, bo_e, 0);
  ln_res_k<<<kBS, 256, 0, stream>>>(enc_x, t1, gamma + 0 * kE, beta + 0 * kE, n1);
  gemm(n1, ffw1, ffb1, ffh, kBS, kFH, kE, 1);
  gemm(ffh, ffw2, ffb2, t1, kBS, kE, kFH, 0);
  ln_res_k<<<kBS, 256, 0, stream>>>(n1, t1, gamma + 1 * kE, beta + 1 * kE, n_enc);

  // ---------------- decoder ----------------
  embed_pe_k<<<kBS, 256, 0, stream>>>(trg, emb_d, dec_x);
  mha(dec_x, dec_x, qkv_m, bqkv_m, wo_m, bo_m, 1);
  ln_res_k<<<kBS, 256, 0, stream>>>(dec_x, t1, gamma + 2 * kE, beta + 2 * kE, n1);  // n1d
  mha(n1, n_enc, qkv_c, bqkv_c, wo_c, bo_c, 0);
  ln_res_k<<<kBS, 256, 0, stream>>>(n1, t1, gamma + 3 * kE, beta + 3 * kE, enc_x);  // n2d
  gemm(enc_x, ffw1 + (size_t)kE * kFH, ffb1 + kFH, ffh, kBS, kFH, kE, 1);
  gemm(ffh, ffw2 + (size_t)kFH * kE, ffb2 + kE, t1, kBS, kE, kFH, 0);
  ln_res_k<<<kBS, 256, 0, stream>>>(enc_x, t1, gamma + 4 * kE, beta + 4 * kE, dec_x); // n3d

  // ---------------- logits + softmax ----------------
  gemm(dec_x, wout, bout, out, kBS, kV, kE, 0);
  softmax_rows_k<<<kBS, 256, 0, stream>>>(out);
}

// Round 2
// 4469.501 us; speedup vs baseline: 2.2372x; 2.2372x over previous
//
#include <hip/hip_runtime.h>
#include <hip/hip_bf16.h>
#include <math.h>

namespace {

constexpr int kB = 2, kS = 1024, kE = 1024, kH = 16, kD = 64, kV = 32000, kFH = 512;
constexpr int kBS = kB * kS;   // 2048 rows
constexpr int kHD = kH * kD;   // 1024

typedef __attribute__((ext_vector_type(8))) short bf16x8;
typedef __attribute__((ext_vector_type(4))) float f32x4;

// ---------------- embedding + positional encoding ----------------
__global__ __launch_bounds__(256) void embed_pe_k(const int* __restrict__ tok,
                                                  const float* __restrict__ emb,
                                                  float* __restrict__ out) {
  int row = blockIdx.x;              // b*S + s
  int s = row & (kS - 1);
  int t = tok[row];
  const float* src = emb + (size_t)t * kE;
  float* dst = out + (size_t)row * kE;
  for (int e = threadIdx.x; e < kE; e += 256) {
    int i = e >> 1;
    float denom = powf(10000.0f, (float)(2 * i) * (1.0f / (float)kE));
    float ang = (float)s / denom;
    float pe = (e & 1) ? cosf(ang) : sinf(ang);
    dst[e] = src[e] + pe;
  }
}

// ---------------- fp32 -> bf16 cast (vectorized) ----------------
__global__ __launch_bounds__(256) void cast_bf16_k(const float* __restrict__ src,
                                                   __hip_bfloat16* __restrict__ dst,
                                                   int n4) {
  int i = blockIdx.x * 256 + threadIdx.x;
  if (i >= n4) return;
  float4 v = ((const float4*)src)[i];
  union { __hip_bfloat16 h[4]; short4 s4; } u;
  u.h[0] = __float2bfloat16(v.x);
  u.h[1] = __float2bfloat16(v.y);
  u.h[2] = __float2bfloat16(v.z);
  u.h[3] = __float2bfloat16(v.w);
  ((short4*)dst)[i] = u.s4;
}

// ---------------- transpose + cast: src[R,C] fp32 -> dst[C,R] bf16 (batched) -------
__global__ __launch_bounds__(256) void tcast_k(const float* __restrict__ src,
                                               __hip_bfloat16* __restrict__ dst,
                                               int R, int C) {
  __shared__ float tile[32][33];
  src += (size_t)blockIdx.z * R * C;
  dst += (size_t)blockIdx.z * R * C;
  int c0 = blockIdx.x * 32, r0 = blockIdx.y * 32;
  int tx = threadIdx.x & 31, ty = threadIdx.x >> 5;   // ty in 0..7
#pragma unroll
  for (int i = 0; i < 32; i += 8)
    tile[ty + i][tx] = src[(size_t)(r0 + ty + i) * C + c0 + tx];
  __syncthreads();
#pragma unroll
  for (int i = 0; i < 32; i += 8)
    dst[(size_t)(c0 + ty + i) * R + r0 + tx] = __float2bfloat16(tile[tx][ty + i]);
}

// ---------------- bf16 MFMA GEMM: C[M,N] = A[M,K] @ Bt[N,K]^T + bias ----------------
// 128x128 tile, BK=32, 4 waves (each 64x64), mfma_f32_16x16x32_bf16.
// LDS linear, global_load_lds width=16, both-sides XOR swizzle kc ^= (row>>1)&3.
__global__ __launch_bounds__(256) void gemm_bf16_k(
    const __hip_bfloat16* __restrict__ A,   // [M,K] bf16
    const __hip_bfloat16* __restrict__ Bt,  // [N,K] bf16
    const float* __restrict__ bias,         // [N]
    float* __restrict__ C,                  // [M,N] fp32
    int M, int N, int K, int relu) {
  __shared__ __align__(16) char As[128 * 64];   // [128 rows][32 bf16] = 8 KB
  __shared__ __align__(16) char Bs[128 * 64];
  const int tid = threadIdx.x;
  const int w = tid >> 6, lane = tid & 63;
  const int wr = w >> 1, wc = w & 1;
  const int bm = blockIdx.y * 128, bn = blockIdx.x * 128;
  const int lr = lane & 15, kg = lane >> 4;

  f32x4 acc[4][4] = {};

  for (int k0 = 0; k0 < K; k0 += 32) {
    // stage A,B tiles: each wave 2 issues x 16B/lane; pre-swizzled global source
#pragma unroll
    for (int t = 0; t < 2; ++t) {
      int slot = (w * 2 + t) * 64 + lane;            // 0..511 (16B slots)
      int row = slot >> 2;
      int kc = (slot & 3) ^ ((row >> 1) & 3);        // inverse swizzle on source
      const __hip_bfloat16* ga = A + (size_t)(bm + row) * K + k0 + kc * 8;
      const __hip_bfloat16* gb = Bt + (size_t)(bn + row) * K + k0 + kc * 8;
      __builtin_amdgcn_global_load_lds(
          (const __attribute__((address_space(1))) void*)ga,
          (__attribute__((address_space(3))) void*)(As + (w * 2 + t) * 1024), 16, 0, 0);
      __builtin_amdgcn_global_load_lds(
          (const __attribute__((address_space(1))) void*)gb,
          (__attribute__((address_space(3))) void*)(Bs + (w * 2 + t) * 1024), 16, 0, 0);
    }
    __syncthreads();
    bf16x8 af[4], bfr[4];
#pragma unroll
    for (int i = 0; i < 4; ++i) {
      int row = wr * 64 + i * 16 + lr;
      af[i] = *(const bf16x8*)(As + row * 64 + ((kg ^ ((row >> 1) & 3)) << 4));
    }
#pragma unroll
    for (int j = 0; j < 4; ++j) {
      int row = wc * 64 + j * 16 + lr;
      bfr[j] = *(const bf16x8*)(Bs + row * 64 + ((kg ^ ((row >> 1) & 3)) << 4));
    }
#pragma unroll
    for (int i = 0; i < 4; ++i)
#pragma unroll
      for (int j = 0; j < 4; ++j)
        acc[i][j] = __builtin_amdgcn_mfma_f32_16x16x32_bf16(af[i], bfr[j], acc[i][j], 0, 0, 0);
    __syncthreads();
  }
  // epilogue: C/D layout col=lane&15, row=(lane>>4)*4+reg
#pragma unroll
  for (int j = 0; j < 4; ++j) {
    int col = bn + wc * 64 + j * 16 + lr;
    float bc = bias[col];
#pragma unroll
    for (int i = 0; i < 4; ++i) {
      int rbase = bm + wr * 64 + i * 16 + kg * 4;
#pragma unroll
      for (int r = 0; r < 4; ++r) {
        float val = acc[i][j][r] + bc;
        if (relu) val = fmaxf(val, 0.0f);
        C[(size_t)(rbase + r) * N + col] = val;
      }
    }
  }
}

// ---------------- fused attention: 8 queries per block ----------------
constexpr int QT = 8;
__global__ __launch_bounds__(256) void attn8_k(const float* __restrict__ q,
                                               const float* __restrict__ k,
                                               const float* __restrict__ v,
                                               float* __restrict__ out, int causal) {
  __shared__ float qs[QT][kD];
  __shared__ float sc[QT][kS];          // 32 KB
  __shared__ float part[4][QT][kD];     // 8 KB
  __shared__ float rsum[QT];
  const int tid = threadIdx.x;
  const int lane = tid & 63, w = tid >> 6;
  const int q0 = blockIdx.x * QT;
  const int h = blockIdx.y, b = blockIdx.z;
  const size_t rs = kHD;
  const float* qbase = q + (size_t)(b * kS + q0) * rs + h * kD;
  for (int i = tid; i < QT * kD; i += 256)
    qs[i >> 6][i & 63] = qbase[(size_t)(i >> 6) * rs + (i & 63)];
  __syncthreads();
  const int smaxT = causal ? (q0 + QT) : kS;
  const float* kbase = k + (size_t)(b * kS) * rs + h * kD;
  for (int s = tid; s < smaxT; s += 256) {
    const float4* kr = (const float4*)(kbase + (size_t)s * rs);
    float accq[QT];
#pragma unroll
    for (int qq = 0; qq < QT; ++qq) accq[qq] = 0.0f;
#pragma unroll
    for (int i = 0; i < 16; ++i) {
      float4 kv = kr[i];
#pragma unroll
      for (int qq = 0; qq < QT; ++qq) {
        float4 qv = ((const float4*)qs[qq])[i];
        accq[qq] += kv.x * qv.x + kv.y * qv.y + kv.z * qv.z + kv.w * qv.w;
      }
    }
#pragma unroll
    for (int qq = 0; qq < QT; ++qq)
      sc[qq][s] = (causal && s > q0 + qq) ? -INFINITY : accq[qq] * 0.125f;
  }
  __syncthreads();
  // softmax: wave w handles queries 2w, 2w+1 (masked entries exp to 0)
#pragma unroll
  for (int qq = 0; qq < 2; ++qq) {
    int qi = w * 2 + qq;
    float m = -INFINITY;
    for (int s = lane; s < smaxT; s += 64) m = fmaxf(m, sc[qi][s]);
#pragma unroll
    for (int o = 32; o > 0; o >>= 1) m = fmaxf(m, __shfl_xor(m, o));
    float sum = 0.0f;
    for (int s = lane; s < smaxT; s += 64) {
      float p = __expf(sc[qi][s] - m);
      sc[qi][s] = p;
      sum += p;
    }
#pragma unroll
    for (int o = 32; o > 0; o >>= 1) sum += __shfl_xor(sum, o);
    if (lane == 0) rsum[qi] = 1.0f / sum;
  }
  __syncthreads();
  // PV: thread (g = s-phase, d)
  const int d = tid & 63, g = tid >> 6;
  float acc[QT];
#pragma unroll
  for (int qq = 0; qq < QT; ++qq) acc[qq] = 0.0f;
  const float* vbase = v + (size_t)(b * kS) * rs + h * kD + d;
  for (int s = g; s < smaxT; s += 4) {
    float vv = vbase[(size_t)s * rs];
#pragma unroll
    for (int qq = 0; qq < QT; ++qq) acc[qq] += sc[qq][s] * vv;
  }
#pragma unroll
  for (int qq = 0; qq < QT; ++qq) part[g][qq][d] = acc[qq];
  __syncthreads();
  for (int i = tid; i < QT * kD; i += 256) {
    int qq = i >> 6, dd = i & 63;
    float o2 = (part[0][qq][dd] + part[1][qq][dd] + part[2][qq][dd] + part[3][qq][dd]) * rsum[qq];
    out[(size_t)(b * kS + q0 + qq) * rs + h * kD + dd] = o2;
  }
}

// ---------------- residual + LayerNorm ----------------
__global__ __launch_bounds__(256) void ln_res_k(const float* __restrict__ a,
                                                const float* __restrict__ b,
                                                const float* __restrict__ gamma,
                                                const float* __restrict__ beta,
                                                float* __restrict__ out) {
  __shared__ float sh[10];
  int row = blockIdx.x;
  const float* ar = a + (size_t)row * kE;
  const float* br = b + (size_t)row * kE;
  int tid = threadIdx.x;
  float t[4], s = 0.0f, q2 = 0.0f;
#pragma unroll
  for (int i = 0; i < 4; ++i) {
    int e = tid + i * 256;
    t[i] = ar[e] + br[e];
    s += t[i];
    q2 += t[i] * t[i];
  }
  for (int o = 32; o > 0; o >>= 1) { s += __shfl_down(s, o); q2 += __shfl_down(q2, o); }
  int lane = tid & 63, wid = tid >> 6;
  if (lane == 0) { sh[wid] = s; sh[4 + wid] = q2; }
  __syncthreads();
  if (tid == 0) {
    float S2 = sh[0] + sh[1] + sh[2] + sh[3];
    float Q2 = sh[4] + sh[5] + sh[6] + sh[7];
    float mean = S2 * (1.0f / kE);
    float var = Q2 * (1.0f / kE) - mean * mean;
    sh[8] = mean;
    sh[9] = rsqrtf(var + 1e-15f);
  }
  __syncthreads();
  float mean = sh[8], inv = sh[9];
#pragma unroll
  for (int i = 0; i < 4; ++i) {
    int e = tid + i * 256;
    out[(size_t)row * kE + e] = gamma[e] * ((t[i] - mean) * inv) + beta[e];
  }
}

// ---------------- row softmax over V (in place) ----------------
__global__ __launch_bounds__(256) void softmax_rows_k(float* __restrict__ x) {
  __shared__ float sh[10];
  int row = blockIdx.x;
  float* xr = x + (size_t)row * kV;
  int tid = threadIdx.x;
  float m = -INFINITY, sum = 0.0f;
  for (int i = tid; i < kV; i += 256) {
    float v2 = xr[i];
    float nm = fmaxf(m, v2);
    sum = sum * __expf(m - nm) + __expf(v2 - nm);
    m = nm;
  }
  for (int o = 32; o > 0; o >>= 1) {
    float om = __shfl_down(m, o), os = __shfl_down(sum, o);
    float nm = fmaxf(m, om);
    sum = sum * __expf(m - nm) + os * __expf(om - nm);
    m = nm;
  }
  int lane = tid & 63, wid = tid >> 6;
  if (lane == 0) { sh[wid] = m; sh[4 + wid] = sum; }
  __syncthreads();
  if (tid == 0) {
    float M = fmaxf(fmaxf(sh[0], sh[1]), fmaxf(sh[2], sh[3]));
    float S2 = sh[4] * __expf(sh[0] - M) + sh[5] * __expf(sh[1] - M) +
               sh[6] * __expf(sh[2] - M) + sh[7] * __expf(sh[3] - M);
    sh[8] = M;
    sh[9] = 1.0f / S2;
  }
  __syncthreads();
  float M = sh[8], rcp = sh[9];
  for (int i = tid; i < kV; i += 256) xr[i] = __expf(xr[i] - M) * rcp;
}

}  // namespace

extern "C" void kernel_launch(void* const* d_in, const int* in_sizes, int n_in,
                              void* d_out, int out_size, void* d_ws, size_t ws_size,
                              hipStream_t stream) {
  const int*   src    = (const int*)d_in[0];
  const int*   trg    = (const int*)d_in[1];
  const float* emb_e  = (const float*)d_in[2];
  const float* emb_d  = (const float*)d_in[3];
  const float* qkv_e  = (const float*)d_in[4];
  const float* bqkv_e = (const float*)d_in[5];
  const float* wo_e   = (const float*)d_in[6];
  const float* bo_e   = (const float*)d_in[7];
  const float* qkv_m  = (const float*)d_in[8];
  const float* bqkv_m = (const float*)d_in[9];
  const float* wo_m   = (const float*)d_in[10];
  const float* bo_m   = (const float*)d_in[11];
  const float* qkv_c  = (const float*)d_in[12];
  const float* bqkv_c = (const float*)d_in[13];
  const float* wo_c   = (const float*)d_in[14];
  const float* bo_c   = (const float*)d_in[15];
  const float* gamma  = (const float*)d_in[16];
  const float* beta   = (const float*)d_in[17];
  const float* ffw1   = (const float*)d_in[18];
  const float* ffb1   = (const float*)d_in[19];
  const float* ffw2   = (const float*)d_in[20];
  const float* ffb2   = (const float*)d_in[21];
  const float* wout   = (const float*)d_in[22];
  const float* bout   = (const float*)d_in[23];
  float* out = (float*)d_out;

  float* w = (float*)d_ws;
  const size_t R = (size_t)kBS * kE;   // 2M floats
  float* enc_x = w + 0 * R;            // later reused as n2d
  float* dec_x = w + 1 * R;            // later reused as n3d
  float* qb    = w + 2 * R;
  float* kb    = w + 3 * R;
  float* vb    = w + 4 * R;
  float* ao    = w + 5 * R;
  float* t1    = w + 6 * R;
  float* n1    = w + 7 * R;            // later reused as n1d
  float* n_enc = w + 8 * R;
  float* ffh   = w + 9 * R;            // 2048*512 fp32 (R/2)
  // bf16 region
  __hip_bfloat16* bb  = (__hip_bfloat16*)(w + 9 * R + R / 2);
  __hip_bfloat16* Ab0 = bb;                                   // R elems
  __hip_bfloat16* Ab1 = bb + R;                               // R elems
  __hip_bfloat16* Wqkv = bb + 2 * R;                          // 3*E*HD
  __hip_bfloat16* Wo   = Wqkv + 3 * (size_t)kE * kHD;         // E*HD
  __hip_bfloat16* Wf1  = Wo + (size_t)kE * kHD;               // E*FH
  __hip_bfloat16* Wf2  = Wf1 + (size_t)kE * kFH;              // FH*E
  __hip_bfloat16* Wv   = Wf2 + (size_t)kFH * kE;              // V*E

  auto cast = [&](const float* s, __hip_bfloat16* d, int n) {
    cast_bf16_k<<<dim3((n / 4 + 255) / 256), 256, 0, stream>>>(s, d, n / 4);
  };
  auto tcast = [&](const float* s, __hip_bfloat16* d, int Rr, int Cc, int batch) {
    tcast_k<<<dim3(Cc / 32, Rr / 32, batch), 256, 0, stream>>>(s, d, Rr, Cc);
  };
  auto gemmb = [&](const __hip_bfloat16* A, const __hip_bfloat16* Bt, const float* bias,
                   float* C, int M, int N, int K, int relu) {
    gemm_bf16_k<<<dim3(N / 128, M / 128), 256, 0, stream>>>(A, Bt, bias, C, M, N, K, relu);
  };

  auto mha = [&](const float* xq, const float* xkv, const float* qkvw, const float* bqkv,
                 const float* wo, const float* bo, int causal) {
    tcast(qkvw, Wqkv, kE, kD, 3 * kH);   // [3,H,E,D] -> [3][HD][E]
    tcast(wo, Wo, kHD, kE, 1);           // [HD,E] -> [E][HD]
    cast(xq, Ab0, kBS * kE);
    const __hip_bfloat16* AKV = Ab0;
    if (xkv != xq) { cast(xkv, Ab1, kBS * kE); AKV = Ab1; }
    gemmb(Ab0, Wqkv,                       bqkv,           qb, kBS, kHD, kE, 0);
    gemmb(AKV, Wqkv + (size_t)kE * kHD,    bqkv + kHD,     kb, kBS, kHD, kE, 0);
    gemmb(AKV, Wqkv + 2 * (size_t)kE * kHD, bqkv + 2 * kHD, vb, kBS, kHD, kE, 0);
    attn8_k<<<dim3(kS / QT, kH, kB), 256, 0, stream>>>(qb, kb, vb, ao, causal);
    cast(ao, Ab0, kBS * kE);
    gemmb(Ab0, Wo, bo, t1, kBS, kE, kHD, 0);
  };

  auto ff = [&](const float* xin, int sel, float* res_out_unused) {
    tcast(ffw1 + (size_t)sel * kE * kFH, Wf1, kE, kFH, 1);   // -> [FH][E]
    tcast(ffw2 + (size_t)sel * kFH * kE, Wf2, kFH, kE, 1);   // -> [E][FH]
    cast(xin, Ab0, kBS * kE);
    gemmb(Ab0, Wf1, ffb1 + (size_t)sel * kFH, ffh, kBS, kFH, kE, 1);
    cast(ffh, Ab1, kBS * kFH);
    gemmb(Ab1, Wf2, ffb2 + (size_t)sel * kE, t1, kBS, kE, kFH, 0);
  };

  // ---------------- encoder ----------------
  embed_pe_k<<<kBS, 256, 0, stream>>>(src, emb_e, enc_x);
  mha(enc_x, enc_x, qkv_e, bqkv_e, wo_e, bo_e, 0);
  ln_res_k<<<kBS, 256, 0, stream>>>(enc_x, t1, gamma + 0 * kE, beta + 0 * kE, n1);
  ff(n1, 0, nullptr);
  ln_res_k<<<kBS, 256, 0, stream>>>(n1, t1, gamma + 1 * kE, beta + 1 * kE, n_enc);

  // ---------------- decoder ----------------
  embed_pe_k<<<kBS, 256, 0, stream>>>(trg, emb_d, dec_x);
  mha(dec_x, dec_x, qkv_m, bqkv_m, wo_m, bo_m, 1);
  ln_res_k<<<kBS, 256, 0, stream>>>(dec_x, t1, gamma + 2 * kE, beta + 2 * kE, n1);  // n1d
  mha(n1, n_enc, qkv_c, bqkv_c, wo_c, bo_c, 0);
  ln_res_k<<<kBS, 256, 0, stream>>>(n1, t1, gamma + 3 * kE, beta + 3 * kE, enc_x);  // n2d
  ff(enc_x, 1, nullptr);
  ln_res_k<<<kBS, 256, 0, stream>>>(enc_x, t1, gamma + 4 * kE, beta + 4 * kE, dec_x); // n3d

  // ---------------- logits + softmax ----------------
  tcast(wout, Wv, kE, kV, 1);            // [E,V] -> [V][E]
  cast(dec_x, Ab0, kBS * kE);
  gemmb(Ab0, Wv, bout, out, kBS, kV, kE, 0);
  softmax_rows_k<<<kBS, 256, 0, stream>>>(out);
}

// Round 3
// 966.698 us; speedup vs baseline: 10.3435x; 4.6235x over previous
//
#include <hip/hip_runtime.h>
#include <hip/hip_bf16.h>
#include <math.h>

namespace {

constexpr int kB = 2, kS = 1024, kE = 1024, kH = 16, kD = 64, kV = 32000, kFH = 512;
constexpr int kBS = kB * kS;   // 2048 rows
constexpr int kHD = kH * kD;   // 1024

typedef __attribute__((ext_vector_type(8))) short bf16x8;
typedef __attribute__((ext_vector_type(4))) float f32x4;

// ---------------- embedding + positional encoding (dual fp32/bf16 out) ------------
__global__ __launch_bounds__(256) void embed_pe_k(const int* __restrict__ tok,
                                                  const float* __restrict__ emb,
                                                  float* __restrict__ out,
                                                  __hip_bfloat16* __restrict__ outb) {
  int row = blockIdx.x;              // b*S + s
  int s = row & (kS - 1);
  int t = tok[row];
  const float* src = emb + (size_t)t * kE;
  float* dst = out + (size_t)row * kE;
  __hip_bfloat16* dstb = outb + (size_t)row * kE;
  for (int e = threadIdx.x; e < kE; e += 256) {
    int i = e >> 1;
    float denom = powf(10000.0f, (float)(2 * i) * (1.0f / (float)kE));
    float ang = (float)s / denom;
    float pe = (e & 1) ? cosf(ang) : sinf(ang);
    float v = src[e] + pe;
    dst[e] = v;
    dstb[e] = __float2bfloat16(v);
  }
}

// ---------------- transpose + cast: src[R,C] fp32 -> dst[C,R] bf16 (batched) -------
__global__ __launch_bounds__(256) void tcast_k(const float* __restrict__ src,
                                               __hip_bfloat16* __restrict__ dst,
                                               int R, int C) {
  __shared__ float tile[32][33];
  src += (size_t)blockIdx.z * R * C;
  dst += (size_t)blockIdx.z * R * C;
  int c0 = blockIdx.x * 32, r0 = blockIdx.y * 32;
  int tx = threadIdx.x & 31, ty = threadIdx.x >> 5;   // ty in 0..7
#pragma unroll
  for (int i = 0; i < 32; i += 8)
    tile[ty + i][tx] = src[(size_t)(r0 + ty + i) * C + c0 + tx];
  __syncthreads();
#pragma unroll
  for (int i = 0; i < 32; i += 8)
    dst[(size_t)(c0 + ty + i) * R + r0 + tx] = __float2bfloat16(tile[tx][ty + i]);
}

// ---------------- bf16 transpose per head: v[BS, sV] -> vt[(b*H+h)*64 + d][S] ------
__global__ __launch_bounds__(256) void vtrans_k(const __hip_bfloat16* __restrict__ v,
                                                int sV, __hip_bfloat16* __restrict__ vt) {
  __shared__ unsigned short tile[32][34];
  int s0 = blockIdx.x * 32, d0 = blockIdx.y * 32, bh = blockIdx.z;
  int b = bh >> 4, h = bh & 15;
  int tx = threadIdx.x & 31, ty = threadIdx.x >> 5;
  const unsigned short* src = (const unsigned short*)v;
  unsigned short* dst = (unsigned short*)vt;
#pragma unroll
  for (int i = 0; i < 32; i += 8)
    tile[ty + i][tx] = src[(size_t)(b * kS + s0 + ty + i) * sV + h * 64 + d0 + tx];
  __syncthreads();
#pragma unroll
  for (int i = 0; i < 32; i += 8)
    dst[(size_t)(bh * 64 + d0 + ty + i) * kS + s0 + tx] = tile[tx][ty + i];
}

// ---------------- bf16 MFMA GEMM: C[M,N] = A[M,K] @ Bt[N,K]^T + bias ----------------
// mode: 0 = fp32 out, 1 = fp32+relu, 2 = bf16 out, 3 = bf16+relu
__global__ __launch_bounds__(256) void gemm_bf16_k(
    const __hip_bfloat16* __restrict__ A,   // [M,K] bf16
    const __hip_bfloat16* __restrict__ Bt,  // [N,K] bf16
    const float* __restrict__ bias,         // [N]
    void* __restrict__ Cout,
    int M, int N, int K, int mode) {
  __shared__ __align__(16) char As[128 * 64];   // [128 rows][32 bf16] = 8 KB
  __shared__ __align__(16) char Bs[128 * 64];
  const int tid = threadIdx.x;
  const int w = tid >> 6, lane = tid & 63;
  const int wr = w >> 1, wc = w & 1;
  const int bm = blockIdx.y * 128, bn = blockIdx.x * 128;
  const int lr = lane & 15, kg = lane >> 4;

  f32x4 acc[4][4] = {};

  for (int k0 = 0; k0 < K; k0 += 32) {
#pragma unroll
    for (int t = 0; t < 2; ++t) {
      int slot = (w * 2 + t) * 64 + lane;            // 0..511 (16B slots)
      int row = slot >> 2;
      int kc = (slot & 3) ^ ((row >> 1) & 3);        // inverse swizzle on source
      const __hip_bfloat16* ga = A + (size_t)(bm + row) * K + k0 + kc * 8;
      const __hip_bfloat16* gb = Bt + (size_t)(bn + row) * K + k0 + kc * 8;
      __builtin_amdgcn_global_load_lds(
          (const __attribute__((address_space(1))) void*)ga,
          (__attribute__((address_space(3))) void*)(As + (w * 2 + t) * 1024), 16, 0, 0);
      __builtin_amdgcn_global_load_lds(
          (const __attribute__((address_space(1))) void*)gb,
          (__attribute__((address_space(3))) void*)(Bs + (w * 2 + t) * 1024), 16, 0, 0);
    }
    __syncthreads();
    bf16x8 af[4], bfr[4];
#pragma unroll
    for (int i = 0; i < 4; ++i) {
      int row = wr * 64 + i * 16 + lr;
      af[i] = *(const bf16x8*)(As + row * 64 + ((kg ^ ((row >> 1) & 3)) << 4));
    }
#pragma unroll
    for (int j = 0; j < 4; ++j) {
      int row = wc * 64 + j * 16 + lr;
      bfr[j] = *(const bf16x8*)(Bs + row * 64 + ((kg ^ ((row >> 1) & 3)) << 4));
    }
#pragma unroll
    for (int i = 0; i < 4; ++i)
#pragma unroll
      for (int j = 0; j < 4; ++j)
        acc[i][j] = __builtin_amdgcn_mfma_f32_16x16x32_bf16(af[i], bfr[j], acc[i][j], 0, 0, 0);
    __syncthreads();
  }
  float* Cf = (float*)Cout;
  __hip_bfloat16* Cb = (__hip_bfloat16*)Cout;
#pragma unroll
  for (int j = 0; j < 4; ++j) {
    int col = bn + wc * 64 + j * 16 + lr;
    float bc = bias[col];
#pragma unroll
    for (int i = 0; i < 4; ++i) {
      int rbase = bm + wr * 64 + i * 16 + kg * 4;
#pragma unroll
      for (int r = 0; r < 4; ++r) {
        float val = acc[i][j][r] + bc;
        if (mode & 1) val = fmaxf(val, 0.0f);
        if (mode < 2) Cf[(size_t)(rbase + r) * N + col] = val;
        else          Cb[(size_t)(rbase + r) * N + col] = __float2bfloat16(val);
      }
    }
  }
}

// ---------------- MFMA flash attention ----------------
// grid (S/64, H, B), 4 waves; wave w owns q rows [q0+16w, q0+16w+16).
// K tile [64 keys][64 d] and Vt tile [64 d][64 keys] staged in LDS (XOR-swizzled).
__global__ __launch_bounds__(256) void attn_mfma_k(
    const __hip_bfloat16* __restrict__ q, int sQ,
    const __hip_bfloat16* __restrict__ k, int sK,
    const __hip_bfloat16* __restrict__ vt,   // [(b*H+h)*64 + d][S]
    __hip_bfloat16* __restrict__ o,          // [BS][HD]
    int causal) {
  __shared__ __align__(16) char Ks[8192];
  __shared__ __align__(16) char Vs[8192];
  __shared__ __align__(16) char Ps[4][2304];   // per-wave P tile [16 q][72 bf16] (144B rows)
  const int tid = threadIdx.x, w = tid >> 6, l = tid & 63;
  const int lr = l & 15, lg = l >> 4;
  const int q0 = blockIdx.x * 64, h = blockIdx.y, b = blockIdx.z;

  // Q fragments (held in registers for the whole kernel)
  const int qrow = q0 + w * 16 + lr;
  const __hip_bfloat16* qp = q + (size_t)(b * kS + qrow) * sQ + h * 64 + lg * 8;
  bf16x8 aQ0 = *(const bf16x8*)qp;
  bf16x8 aQ1 = *(const bf16x8*)(qp + 32);

  f32x4 oacc[4] = {};
  float mrun[4], lrun[4];
#pragma unroll
  for (int r = 0; r < 4; ++r) { mrun[r] = -INFINITY; lrun[r] = 0.0f; }

  const int ntiles = causal ? ((q0 >> 6) + 1) : (kS >> 6);
  const int diagT = causal ? (q0 >> 6) : -1;
  const char* kbase = (const char*)(k + (size_t)(b * kS) * sK + h * 64);
  const char* vbase = (const char*)(vt + (size_t)((b * kH + h) * 64) * kS);
  char* Pw = Ps[w];

  for (int t = 0; t < ntiles; ++t) {
    const int kv0 = t * 64;
    __syncthreads();   // previous tile fully consumed
#pragma unroll
    for (int i = 0; i < 2; ++i) {
      int slot = w * 128 + i * 64 + l;
      int row = slot >> 3, sl = slot & 7, c = sl ^ (row & 7);
      const char* gk = kbase + (size_t)(kv0 + row) * sK * 2 + c * 16;
      const char* gv = vbase + (size_t)row * kS * 2 + kv0 * 2 + c * 16;
      __builtin_amdgcn_global_load_lds(
          (const __attribute__((address_space(1))) void*)gk,
          (__attribute__((address_space(3))) void*)(Ks + (w * 128 + i * 64) * 16), 16, 0, 0);
      __builtin_amdgcn_global_load_lds(
          (const __attribute__((address_space(1))) void*)gv,
          (__attribute__((address_space(3))) void*)(Vs + (w * 128 + i * 64) * 16), 16, 0, 0);
    }
    __syncthreads();   // staging complete

    // ---- S = Q @ K^T  (16q x 64keys per wave) ----
    f32x4 sacc[4] = {};
#pragma unroll
    for (int nf = 0; nf < 4; ++nf) {
      int key = nf * 16 + lr;
#pragma unroll
      for (int kf = 0; kf < 2; ++kf) {
        int ch = (lg + kf * 4) ^ (key & 7);
        bf16x8 bK = *(const bf16x8*)(Ks + key * 128 + ch * 16);
        sacc[nf] = __builtin_amdgcn_mfma_f32_16x16x32_bf16(kf ? aQ1 : aQ0, bK, sacc[nf], 0, 0, 0);
      }
    }

    // ---- online softmax (per q-row; rows live in (lg, r) groups) ----
#pragma unroll
    for (int r = 0; r < 4; ++r) {
      int row16 = lg * 4 + r;
      int qg = q0 + w * 16 + row16;
      float sv[4];
#pragma unroll
      for (int nf = 0; nf < 4; ++nf) {
        float s = sacc[nf][r] * 0.125f;
        if (t == diagT && (kv0 + nf * 16 + lr) > qg) s = -INFINITY;
        sv[nf] = s;
      }
      float mx = fmaxf(fmaxf(sv[0], sv[1]), fmaxf(sv[2], sv[3]));
#pragma unroll
      for (int m = 1; m < 16; m <<= 1) mx = fmaxf(mx, __shfl_xor(mx, m));
      float mnew = fmaxf(mrun[r], mx);
      float sc = __expf(mrun[r] - mnew);
      mrun[r] = mnew;
      float rs = 0.0f;
#pragma unroll
      for (int nf = 0; nf < 4; ++nf) {
        float p = __expf(sv[nf] - mnew);
        rs += p;
        *(__hip_bfloat16*)(Pw + row16 * 144 + (nf * 16 + lr) * 2) = __float2bfloat16(p);
      }
#pragma unroll
      for (int m = 1; m < 16; m <<= 1) rs += __shfl_xor(rs, m);
      lrun[r] = lrun[r] * sc + rs;
#pragma unroll
      for (int nfd = 0; nfd < 4; ++nfd) oacc[nfd][r] *= sc;
    }

    // ---- O += P @ V ----
    bf16x8 aP0 = *(const bf16x8*)(Pw + lr * 144 + (lg * 8) * 2);
    bf16x8 aP1 = *(const bf16x8*)(Pw + lr * 144 + (lg * 8 + 32) * 2);
#pragma unroll
    for (int nfd = 0; nfd < 4; ++nfd) {
      int d = nfd * 16 + lr;
#pragma unroll
      for (int kf = 0; kf < 2; ++kf) {
        int ch = (lg + kf * 4) ^ (d & 7);
        bf16x8 bV = *(const bf16x8*)(Vs + d * 128 + ch * 16);
        oacc[nfd] = __builtin_amdgcn_mfma_f32_16x16x32_bf16(kf ? aP1 : aP0, bV, oacc[nfd], 0, 0, 0);
      }
    }
  }

  // ---- epilogue: divide by row sum, write bf16 ----
#pragma unroll
  for (int r = 0; r < 4; ++r) {
    float inv = 1.0f / lrun[r];
    int rowg = q0 + w * 16 + lg * 4 + r;
#pragma unroll
    for (int nfd = 0; nfd < 4; ++nfd)
      o[(size_t)(b * kS + rowg) * kHD + h * 64 + nfd * 16 + lr] =
          __float2bfloat16(oacc[nfd][r] * inv);
  }
}

// ---------------- residual + LayerNorm (dual fp32/bf16 out) ----------------
__global__ __launch_bounds__(256) void ln_res_k(const float* __restrict__ a,
                                                const float* __restrict__ b,
                                                const float* __restrict__ gamma,
                                                const float* __restrict__ beta,
                                                float* __restrict__ out,
                                                __hip_bfloat16* __restrict__ outb) {
  __shared__ float sh[10];
  int row = blockIdx.x;
  const float* ar = a + (size_t)row * kE;
  const float* br = b + (size_t)row * kE;
  int tid = threadIdx.x;
  float t[4], s = 0.0f, q2 = 0.0f;
#pragma unroll
  for (int i = 0; i < 4; ++i) {
    int e = tid + i * 256;
    t[i] = ar[e] + br[e];
    s += t[i];
    q2 += t[i] * t[i];
  }
  for (int o = 32; o > 0; o >>= 1) { s += __shfl_down(s, o); q2 += __shfl_down(q2, o); }
  int lane = tid & 63, wid = tid >> 6;
  if (lane == 0) { sh[wid] = s; sh[4 + wid] = q2; }
  __syncthreads();
  if (tid == 0) {
    float S2 = sh[0] + sh[1] + sh[2] + sh[3];
    float Q2 = sh[4] + sh[5] + sh[6] + sh[7];
    float mean = S2 * (1.0f / kE);
    float var = Q2 * (1.0f / kE) - mean * mean;
    sh[8] = mean;
    sh[9] = rsqrtf(var + 1e-15f);
  }
  __syncthreads();
  float mean = sh[8], inv = sh[9];
#pragma unroll
  for (int i = 0; i < 4; ++i) {
    int e = tid + i * 256;
    float v = gamma[e] * ((t[i] - mean) * inv) + beta[e];
    out[(size_t)row * kE + e] = v;
    outb[(size_t)row * kE + e] = __float2bfloat16(v);
  }
}

// ---------------- row softmax over V (in place) ----------------
__global__ __launch_bounds__(256) void softmax_rows_k(float* __restrict__ x) {
  __shared__ float sh[10];
  int row = blockIdx.x;
  float* xr = x + (size_t)row * kV;
  int tid = threadIdx.x;
  float m = -INFINITY, sum = 0.0f;
  for (int i = tid; i < kV; i += 256) {
    float v2 = xr[i];
    float nm = fmaxf(m, v2);
    sum = sum * __expf(m - nm) + __expf(v2 - nm);
    m = nm;
  }
  for (int o = 32; o > 0; o >>= 1) {
    float om = __shfl_down(m, o), os = __shfl_down(sum, o);
    float nm = fmaxf(m, om);
    sum = sum * __expf(m - nm) + os * __expf(om - nm);
    m = nm;
  }
  int lane = tid & 63, wid = tid >> 6;
  if (lane == 0) { sh[wid] = m; sh[4 + wid] = sum; }
  __syncthreads();
  if (tid == 0) {
    float M = fmaxf(fmaxf(sh[0], sh[1]), fmaxf(sh[2], sh[3]));
    float S2 = sh[4] * __expf(sh[0] - M) + sh[5] * __expf(sh[1] - M) +
               sh[6] * __expf(sh[2] - M) + sh[7] * __expf(sh[3] - M);
    sh[8] = M;
    sh[9] = 1.0f / S2;
  }
  __syncthreads();
  float M = sh[8], rcp = sh[9];
  for (int i = tid; i < kV; i += 256) xr[i] = __expf(xr[i] - M) * rcp;
}

}  // namespace

extern "C" void kernel_launch(void* const* d_in, const int* in_sizes, int n_in,
                              void* d_out, int out_size, void* d_ws, size_t ws_size,
                              hipStream_t stream) {
  const int*   src    = (const int*)d_in[0];
  const int*   trg    = (const int*)d_in[1];
  const float* emb_e  = (const float*)d_in[2];
  const float* emb_d  = (const float*)d_in[3];
  const float* qkv_e  = (const float*)d_in[4];
  const float* bqkv_e = (const float*)d_in[5];
  const float* wo_e   = (const float*)d_in[6];
  const float* bo_e   = (const float*)d_in[7];
  const float* qkv_m  = (const float*)d_in[8];
  const float* bqkv_m = (const float*)d_in[9];
  const float* wo_m   = (const float*)d_in[10];
  const float* bo_m   = (const float*)d_in[11];
  const float* qkv_c  = (const float*)d_in[12];
  const float* bqkv_c = (const float*)d_in[13];
  const float* wo_c   = (const float*)d_in[14];
  const float* bo_c   = (const float*)d_in[15];
  const float* gamma  = (const float*)d_in[16];
  const float* beta   = (const float*)d_in[17];
  const float* ffw1   = (const float*)d_in[18];
  const float* ffb1   = (const float*)d_in[19];
  const float* ffw2   = (const float*)d_in[20];
  const float* ffb2   = (const float*)d_in[21];
  const float* wout   = (const float*)d_in[22];
  const float* bout   = (const float*)d_in[23];
  float* out = (float*)d_out;

  float* w = (float*)d_ws;
  const size_t R = (size_t)kBS * kE;   // 2M elements
  // fp32 region (5R floats)
  float* enc_x = w + 0 * R;            // reused as n2d
  float* dec_x = w + 1 * R;            // reused as n3d
  float* t1    = w + 2 * R;
  float* n1    = w + 3 * R;            // reused as n1d
  float* n_enc = w + 4 * R;
  // bf16 region
  __hip_bfloat16* bb     = (__hip_bfloat16*)(w + 5 * R);
  __hip_bfloat16* enc_xb = bb;                       // R
  __hip_bfloat16* dec_xb = enc_xb + R;               // R
  __hip_bfloat16* n1b    = dec_xb + R;               // R
  __hip_bfloat16* n_encb = n1b + R;                  // R
  __hip_bfloat16* qkvb   = n_encb + R;               // 3R   [BS, 3HD]
  __hip_bfloat16* kvb    = qkvb + 3 * R;             // 2R   [BS, 2HD]
  __hip_bfloat16* qb1    = kvb + 2 * R;              // R    [BS, HD]
  __hip_bfloat16* vtb    = qb1 + R;                  // R    [B*H*64, S]
  __hip_bfloat16* ao16   = vtb + R;                  // R
  __hip_bfloat16* ffhb   = ao16 + R;                 // R/2
  __hip_bfloat16* Wqkv   = ffhb + R / 2;             // 1.5R  [3HD, E]
  __hip_bfloat16* Wo     = Wqkv + 3 * (size_t)kE * kHD / 2 * 2;  // keep simple below
  // (recompute cleanly)
  Wqkv = ffhb + R / 2;
  Wo   = Wqkv + (size_t)3 * kHD * kE;                // 0.5R  [E rows? no: [E, HD] -> [HD... ] see tcast use
  __hip_bfloat16* Wf1 = Wo + (size_t)kE * kHD;       // [FH, E]
  __hip_bfloat16* Wf2 = Wf1 + (size_t)kFH * kE;      // [E, FH]
  __hip_bfloat16* Wv  = Wf2 + (size_t)kE * kFH;      // [V, E]

  auto tcast = [&](const float* s, __hip_bfloat16* d, int Rr, int Cc, int batch) {
    tcast_k<<<dim3(Cc / 32, Rr / 32, batch), 256, 0, stream>>>(s, d, Rr, Cc);
  };
  auto gemmb = [&](const __hip_bfloat16* A, const __hip_bfloat16* Bt, const float* bias,
                   void* C, int M, int N, int K, int mode) {
    gemm_bf16_k<<<dim3(N / 128, M / 128), 256, 0, stream>>>(A, Bt, bias, C, M, N, K, mode);
  };
  auto vtrans = [&](const __hip_bfloat16* v, int sV) {
    vtrans_k<<<dim3(kS / 32, kD / 32, kB * kH), 256, 0, stream>>>(v, sV, vtb);
  };
  auto attn = [&](const __hip_bfloat16* q, int sQ, const __hip_bfloat16* k, int sK,
                  int causal) {
    attn_mfma_k<<<dim3(kS / 64, kH, kB), 256, 0, stream>>>(q, sQ, k, sK, vtb, ao16, causal);
  };
  auto ln = [&](const float* a, const float* b2, int sel, float* o1, __hip_bfloat16* o2) {
    ln_res_k<<<kBS, 256, 0, stream>>>(a, b2, gamma + sel * kE, beta + sel * kE, o1, o2);
  };

  // ---------------- encoder ----------------
  embed_pe_k<<<kBS, 256, 0, stream>>>(src, emb_e, enc_x, enc_xb);
  tcast(qkv_e, Wqkv, kE, kD, 3 * kH);
  tcast(wo_e, Wo, kHD, kE, 1);
  gemmb(enc_xb, Wqkv, bqkv_e, qkvb, kBS, 3 * kHD, kE, 2);
  vtrans(qkvb + 2 * kHD, 3 * kHD);
  attn(qkvb, 3 * kHD, qkvb + kHD, 3 * kHD, 0);
  gemmb(ao16, Wo, bo_e, t1, kBS, kE, kHD, 0);
  ln(enc_x, t1, 0, n1, n1b);
  tcast(ffw1, Wf1, kE, kFH, 1);
  tcast(ffw2, Wf2, kFH, kE, 1);
  gemmb(n1b, Wf1, ffb1, ffhb, kBS, kFH, kE, 3);
  gemmb(ffhb, Wf2, ffb2, t1, kBS, kE, kFH, 0);
  ln(n1, t1, 1, n_enc, n_encb);

  // ---------------- decoder ----------------
  embed_pe_k<<<kBS, 256, 0, stream>>>(trg, emb_d, dec_x, dec_xb);
  tcast(qkv_m, Wqkv, kE, kD, 3 * kH);
  tcast(wo_m, Wo, kHD, kE, 1);
  gemmb(dec_xb, Wqkv, bqkv_m, qkvb, kBS, 3 * kHD, kE, 2);
  vtrans(qkvb + 2 * kHD, 3 * kHD);
  attn(qkvb, 3 * kHD, qkvb + kHD, 3 * kHD, 1);
  gemmb(ao16, Wo, bo_m, t1, kBS, kE, kHD, 0);
  ln(dec_x, t1, 2, n1, n1b);   // n1d

  tcast(qkv_c, Wqkv, kE, kD, 3 * kH);
  tcast(wo_c, Wo, kHD, kE, 1);
  gemmb(n1b, Wqkv, bqkv_c, qb1, kBS, kHD, kE, 2);
  gemmb(n_encb, Wqkv + (size_t)kHD * kE, bqkv_c + kHD, kvb, kBS, 2 * kHD, kE, 2);
  vtrans(kvb + kHD, 2 * kHD);
  attn(qb1, kHD, kvb, 2 * kHD, 0);
  gemmb(ao16, Wo, bo_c, t1, kBS, kE, kHD, 0);
  ln(n1, t1, 3, enc_x, enc_xb);  // n2d

  tcast(ffw1 + (size_t)kE * kFH, Wf1, kE, kFH, 1);
  tcast(ffw2 + (size_t)kFH * kE, Wf2, kFH, kE, 1);
  gemmb(enc_xb, Wf1, ffb1 + kFH, ffhb, kBS, kFH, kE, 3);
  gemmb(ffhb, Wf2, ffb2 + kE, t1, kBS, kE, kFH, 0);
  ln(enc_x, t1, 4, dec_x, dec_xb);  // n3d

  // ---------------- logits + softmax ----------------
  tcast(wout, Wv, kE, kV, 1);
  gemmb(dec_xb, Wv, bout, out, kBS, kV, kE, 0);
  softmax_rows_k<<<kBS, 256, 0, stream>>>(out);
}

// Round 4
// 890.387 us; speedup vs baseline: 11.2300x; 1.0857x over previous
//
#include <hip/hip_runtime.h>
#include <hip/hip_bf16.h>
#include <math.h>

namespace {

constexpr int kB = 2, kS = 1024, kE = 1024, kH = 16, kD = 64, kV = 32000, kFH = 512;
constexpr int kBS = kB * kS;   // 2048 rows
constexpr int kHD = kH * kD;   // 1024

typedef __attribute__((ext_vector_type(8))) short bf16x8;
typedef __attribute__((ext_vector_type(4))) float f32x4;

// ---------------- positional-encoding table: pe[s][e], s<kS ----------------
__global__ __launch_bounds__(256) void pe_table_k(float* __restrict__ pe) {
  int s = blockIdx.x;
  float* dst = pe + (size_t)s * kE;
  for (int e = threadIdx.x; e < kE; e += 256) {
    int i = e >> 1;
    float denom = powf(10000.0f, (float)(2 * i) * (1.0f / (float)kE));
    float ang = (float)s / denom;
    dst[e] = (e & 1) ? cosf(ang) : sinf(ang);
  }
}

// ---------------- embedding + PE (dual fp32/bf16 out) ----------------
__global__ __launch_bounds__(256) void embed_pe_k(const int* __restrict__ tok,
                                                  const float* __restrict__ emb,
                                                  const float* __restrict__ pe,
                                                  float* __restrict__ out,
                                                  __hip_bfloat16* __restrict__ outb) {
  int row = blockIdx.x;              // b*S + s
  int s = row & (kS - 1);
  int t = tok[row];
  const float4* src = (const float4*)(emb + (size_t)t * kE);
  const float4* per = (const float4*)(pe + (size_t)s * kE);
  float4* dst = (float4*)(out + (size_t)row * kE);
  __hip_bfloat16* dstb = outb + (size_t)row * kE;
  for (int e4 = threadIdx.x; e4 < kE / 4; e4 += 256) {
    float4 a = src[e4], p = per[e4];
    float4 v = make_float4(a.x + p.x, a.y + p.y, a.z + p.z, a.w + p.w);
    dst[e4] = v;
    union { __hip_bfloat16 h[4]; short4 s4; } u;
    u.h[0] = __float2bfloat16(v.x); u.h[1] = __float2bfloat16(v.y);
    u.h[2] = __float2bfloat16(v.z); u.h[3] = __float2bfloat16(v.w);
    ((short4*)dstb)[e4] = u.s4;
  }
}

// ---------------- transpose + cast: src[R,C] fp32 -> dst[C,R] bf16 (batched) -------
__global__ __launch_bounds__(256) void tcast_k(const float* __restrict__ src,
                                               __hip_bfloat16* __restrict__ dst,
                                               int R, int C) {
  __shared__ float tile[32][33];
  src += (size_t)blockIdx.z * R * C;
  dst += (size_t)blockIdx.z * R * C;
  int c0 = blockIdx.x * 32, r0 = blockIdx.y * 32;
  int tx = threadIdx.x & 31, ty = threadIdx.x >> 5;   // ty in 0..7
#pragma unroll
  for (int i = 0; i < 32; i += 8)
    tile[ty + i][tx] = src[(size_t)(r0 + ty + i) * C + c0 + tx];
  __syncthreads();
#pragma unroll
  for (int i = 0; i < 32; i += 8)
    dst[(size_t)(c0 + ty + i) * R + r0 + tx] = __float2bfloat16(tile[tx][ty + i]);
}

// ---------------- bf16 transpose per head: v[BS, sV] -> vt[(b*H+h)*64 + d][S] ------
__global__ __launch_bounds__(256) void vtrans_k(const __hip_bfloat16* __restrict__ v,
                                                int sV, __hip_bfloat16* __restrict__ vt) {
  __shared__ unsigned short tile[32][34];
  int s0 = blockIdx.x * 32, d0 = blockIdx.y * 32, bh = blockIdx.z;
  int b = bh >> 4, h = bh & 15;
  int tx = threadIdx.x & 31, ty = threadIdx.x >> 5;
  const unsigned short* src = (const unsigned short*)v;
  unsigned short* dst = (unsigned short*)vt;
#pragma unroll
  for (int i = 0; i < 32; i += 8)
    tile[ty + i][tx] = src[(size_t)(b * kS + s0 + ty + i) * sV + h * 64 + d0 + tx];
  __syncthreads();
#pragma unroll
  for (int i = 0; i < 32; i += 8)
    dst[(size_t)(bh * 64 + d0 + ty + i) * kS + s0 + tx] = tile[tx][ty + i];
}

// ---------------- bf16 MFMA GEMM: C[M,N] = A[M,K] @ Bt[N,K]^T + bias ----------------
// 1D grid (nwg % 8 == 0). XCD swizzle + M-fastest decomposition for B-panel L2 reuse.
// mode: 0 = fp32 out, 1 = fp32+relu, 2 = bf16 out, 3 = bf16+relu
__global__ __launch_bounds__(256) void gemm_bf16_k(
    const __hip_bfloat16* __restrict__ A,   // [M,K] bf16
    const __hip_bfloat16* __restrict__ Bt,  // [N,K] bf16
    const float* __restrict__ bias,         // [N]
    void* __restrict__ Cout,
    int N, int K, int mode, int gridM) {
  __shared__ __align__(16) char As[128 * 64];   // [128 rows][32 bf16] = 8 KB
  __shared__ __align__(16) char Bs[128 * 64];
  const int nwg = gridDim.x;
  const int id = blockIdx.x;
  const int swz = (id & 7) * (nwg >> 3) + (id >> 3);
  const int bm = (swz % gridM) * 128;
  const int bn = (swz / gridM) * 128;
  const int tid = threadIdx.x;
  const int w = tid >> 6, lane = tid & 63;
  const int wr = w >> 1, wc = w & 1;
  const int lr = lane & 15, kg = lane >> 4;

  f32x4 acc[4][4] = {};

  for (int k0 = 0; k0 < K; k0 += 32) {
#pragma unroll
    for (int t = 0; t < 2; ++t) {
      int slot = (w * 2 + t) * 64 + lane;            // 0..511 (16B slots)
      int row = slot >> 2;
      int kc = (slot & 3) ^ ((row >> 1) & 3);        // inverse swizzle on source
      const __hip_bfloat16* ga = A + (size_t)(bm + row) * K + k0 + kc * 8;
      const __hip_bfloat16* gb = Bt + (size_t)(bn + row) * K + k0 + kc * 8;
      __builtin_amdgcn_global_load_lds(
          (const __attribute__((address_space(1))) void*)ga,
          (__attribute__((address_space(3))) void*)(As + (w * 2 + t) * 1024), 16, 0, 0);
      __builtin_amdgcn_global_load_lds(
          (const __attribute__((address_space(1))) void*)gb,
          (__attribute__((address_space(3))) void*)(Bs + (w * 2 + t) * 1024), 16, 0, 0);
    }
    __syncthreads();
    bf16x8 af[4], bfr[4];
#pragma unroll
    for (int i = 0; i < 4; ++i) {
      int row = wr * 64 + i * 16 + lr;
      af[i] = *(const bf16x8*)(As + row * 64 + ((kg ^ ((row >> 1) & 3)) << 4));
    }
#pragma unroll
    for (int j = 0; j < 4; ++j) {
      int row = wc * 64 + j * 16 + lr;
      bfr[j] = *(const bf16x8*)(Bs + row * 64 + ((kg ^ ((row >> 1) & 3)) << 4));
    }
#pragma unroll
    for (int i = 0; i < 4; ++i)
#pragma unroll
      for (int j = 0; j < 4; ++j)
        acc[i][j] = __builtin_amdgcn_mfma_f32_16x16x32_bf16(af[i], bfr[j], acc[i][j], 0, 0, 0);
    __syncthreads();
  }
  float* Cf = (float*)Cout;
  __hip_bfloat16* Cb = (__hip_bfloat16*)Cout;
#pragma unroll
  for (int j = 0; j < 4; ++j) {
    int col = bn + wc * 64 + j * 16 + lr;
    float bc = bias[col];
#pragma unroll
    for (int i = 0; i < 4; ++i) {
      int rbase = bm + wr * 64 + i * 16 + kg * 4;
#pragma unroll
      for (int r = 0; r < 4; ++r) {
        float val = acc[i][j][r] + bc;
        if (mode & 1) val = fmaxf(val, 0.0f);
        if (mode < 2) Cf[(size_t)(rbase + r) * N + col] = val;
        else          Cb[(size_t)(rbase + r) * N + col] = __float2bfloat16(val);
      }
    }
  }
}

// ---------------- MFMA flash attention ----------------
__global__ __launch_bounds__(256) void attn_mfma_k(
    const __hip_bfloat16* __restrict__ q, int sQ,
    const __hip_bfloat16* __restrict__ k, int sK,
    const __hip_bfloat16* __restrict__ vt,   // [(b*H+h)*64 + d][S]
    __hip_bfloat16* __restrict__ o,          // [BS][HD]
    int causal) {
  __shared__ __align__(16) char Ks[8192];
  __shared__ __align__(16) char Vs[8192];
  __shared__ __align__(16) char Ps[4][2304];   // per-wave P tile [16 q][72 bf16]
  const int tid = threadIdx.x, w = tid >> 6, l = tid & 63;
  const int lr = l & 15, lg = l >> 4;
  const int q0 = blockIdx.x * 64, h = blockIdx.y, b = blockIdx.z;

  const int qrow = q0 + w * 16 + lr;
  const __hip_bfloat16* qp = q + (size_t)(b * kS + qrow) * sQ + h * 64 + lg * 8;
  bf16x8 aQ0 = *(const bf16x8*)qp;
  bf16x8 aQ1 = *(const bf16x8*)(qp + 32);

  f32x4 oacc[4] = {};
  float mrun[4], lrun[4];
#pragma unroll
  for (int r = 0; r < 4; ++r) { mrun[r] = -INFINITY; lrun[r] = 0.0f; }

  const int ntiles = causal ? ((q0 >> 6) + 1) : (kS >> 6);
  const int diagT = causal ? (q0 >> 6) : -1;
  const char* kbase = (const char*)(k + (size_t)(b * kS) * sK + h * 64);
  const char* vbase = (const char*)(vt + (size_t)((b * kH + h) * 64) * kS);
  char* Pw = Ps[w];

  for (int t = 0; t < ntiles; ++t) {
    const int kv0 = t * 64;
    __syncthreads();
#pragma unroll
    for (int i = 0; i < 2; ++i) {
      int slot = w * 128 + i * 64 + l;
      int row = slot >> 3, sl = slot & 7, c = sl ^ (row & 7);
      const char* gk = kbase + (size_t)(kv0 + row) * sK * 2 + c * 16;
      const char* gv = vbase + (size_t)row * kS * 2 + kv0 * 2 + c * 16;
      __builtin_amdgcn_global_load_lds(
          (const __attribute__((address_space(1))) void*)gk,
          (__attribute__((address_space(3))) void*)(Ks + (w * 128 + i * 64) * 16), 16, 0, 0);
      __builtin_amdgcn_global_load_lds(
          (const __attribute__((address_space(1))) void*)gv,
          (__attribute__((address_space(3))) void*)(Vs + (w * 128 + i * 64) * 16), 16, 0, 0);
    }
    __syncthreads();

    // ---- S = Q @ K^T ----
    f32x4 sacc[4] = {};
#pragma unroll
    for (int nf = 0; nf < 4; ++nf) {
      int key = nf * 16 + lr;
#pragma unroll
      for (int kf = 0; kf < 2; ++kf) {
        int ch = (lg + kf * 4) ^ (key & 7);
        bf16x8 bK = *(const bf16x8*)(Ks + key * 128 + ch * 16);
        sacc[nf] = __builtin_amdgcn_mfma_f32_16x16x32_bf16(kf ? aQ1 : aQ0, bK, sacc[nf], 0, 0, 0);
      }
    }

    // ---- online softmax ----
#pragma unroll
    for (int r = 0; r < 4; ++r) {
      int row16 = lg * 4 + r;
      int qg = q0 + w * 16 + row16;
      float sv[4];
#pragma unroll
      for (int nf = 0; nf < 4; ++nf) {
        float s = sacc[nf][r] * 0.125f;
        if (t == diagT && (kv0 + nf * 16 + lr) > qg) s = -INFINITY;
        sv[nf] = s;
      }
      float mx = fmaxf(fmaxf(sv[0], sv[1]), fmaxf(sv[2], sv[3]));
#pragma unroll
      for (int m = 1; m < 16; m <<= 1) mx = fmaxf(mx, __shfl_xor(mx, m));
      float mnew = fmaxf(mrun[r], mx);
      float sc = __expf(mrun[r] - mnew);
      mrun[r] = mnew;
      float rs = 0.0f;
#pragma unroll
      for (int nf = 0; nf < 4; ++nf) {
        float p = __expf(sv[nf] - mnew);
        rs += p;
        *(__hip_bfloat16*)(Pw + row16 * 144 + (nf * 16 + lr) * 2) = __float2bfloat16(p);
      }
#pragma unroll
      for (int m = 1; m < 16; m <<= 1) rs += __shfl_xor(rs, m);
      lrun[r] = lrun[r] * sc + rs;
#pragma unroll
      for (int nfd = 0; nfd < 4; ++nfd) oacc[nfd][r] *= sc;
    }

    // ---- O += P @ V ----
    bf16x8 aP0 = *(const bf16x8*)(Pw + lr * 144 + (lg * 8) * 2);
    bf16x8 aP1 = *(const bf16x8*)(Pw + lr * 144 + (lg * 8 + 32) * 2);
#pragma unroll
    for (int nfd = 0; nfd < 4; ++nfd) {
      int d = nfd * 16 + lr;
#pragma unroll
      for (int kf = 0; kf < 2; ++kf) {
        int ch = (lg + kf * 4) ^ (d & 7);
        bf16x8 bV = *(const bf16x8*)(Vs + d * 128 + ch * 16);
        oacc[nfd] = __builtin_amdgcn_mfma_f32_16x16x32_bf16(kf ? aP1 : aP0, bV, oacc[nfd], 0, 0, 0);
      }
    }
  }

#pragma unroll
  for (int r = 0; r < 4; ++r) {
    float inv = 1.0f / lrun[r];
    int rowg = q0 + w * 16 + lg * 4 + r;
#pragma unroll
    for (int nfd = 0; nfd < 4; ++nfd)
      o[(size_t)(b * kS + rowg) * kHD + h * 64 + nfd * 16 + lr] =
          __float2bfloat16(oacc[nfd][r] * inv);
  }
}

// ---------------- residual + LayerNorm (dual fp32/bf16 out) ----------------
__global__ __launch_bounds__(256) void ln_res_k(const float* __restrict__ a,
                                                const float* __restrict__ b,
                                                const float* __restrict__ gamma,
                                                const float* __restrict__ beta,
                                                float* __restrict__ out,
                                                __hip_bfloat16* __restrict__ outb) {
  __shared__ float sh[10];
  int row = blockIdx.x;
  const float* ar = a + (size_t)row * kE;
  const float* br = b + (size_t)row * kE;
  int tid = threadIdx.x;
  float t[4], s = 0.0f, q2 = 0.0f;
#pragma unroll
  for (int i = 0; i < 4; ++i) {
    int e = tid + i * 256;
    t[i] = ar[e] + br[e];
    s += t[i];
    q2 += t[i] * t[i];
  }
  for (int o = 32; o > 0; o >>= 1) { s += __shfl_down(s, o); q2 += __shfl_down(q2, o); }
  int lane = tid & 63, wid = tid >> 6;
  if (lane == 0) { sh[wid] = s; sh[4 + wid] = q2; }
  __syncthreads();
  if (tid == 0) {
    float S2 = sh[0] + sh[1] + sh[2] + sh[3];
    float Q2 = sh[4] + sh[5] + sh[6] + sh[7];
    float mean = S2 * (1.0f / kE);
    float var = Q2 * (1.0f / kE) - mean * mean;
    sh[8] = mean;
    sh[9] = rsqrtf(var + 1e-15f);
  }
  __syncthreads();
  float mean = sh[8], inv = sh[9];
#pragma unroll
  for (int i = 0; i < 4; ++i) {
    int e = tid + i * 256;
    float v = gamma[e] * ((t[i] - mean) * inv) + beta[e];
    out[(size_t)row * kE + e] = v;
    outb[(size_t)row * kE + e] = __float2bfloat16(v);
  }
}

// ---------------- row softmax over V (in place, float4) ----------------
__global__ __launch_bounds__(256) void softmax_rows_k(float* __restrict__ x) {
  __shared__ float sh[10];
  int row = blockIdx.x;
  float* xr = x + (size_t)row * kV;
  float4* x4 = (float4*)xr;
  const int n4 = kV / 4;   // 8000
  int tid = threadIdx.x;
  float m = -INFINITY, sum = 0.0f;
  for (int i = tid; i < n4; i += 256) {
    float4 v = x4[i];
    float mx = fmaxf(fmaxf(v.x, v.y), fmaxf(v.z, v.w));
    float nm = fmaxf(m, mx);
    sum = sum * __expf(m - nm) + __expf(v.x - nm) + __expf(v.y - nm) +
          __expf(v.z - nm) + __expf(v.w - nm);
    m = nm;
  }
  for (int o = 32; o > 0; o >>= 1) {
    float om = __shfl_down(m, o), os = __shfl_down(sum, o);
    float nm = fmaxf(m, om);
    sum = sum * __expf(m - nm) + os * __expf(om - nm);
    m = nm;
  }
  int lane = tid & 63, wid = tid >> 6;
  if (lane == 0) { sh[wid] = m; sh[4 + wid] = sum; }
  __syncthreads();
  if (tid == 0) {
    float M = fmaxf(fmaxf(sh[0], sh[1]), fmaxf(sh[2], sh[3]));
    float S2 = sh[4] * __expf(sh[0] - M) + sh[5] * __expf(sh[1] - M) +
               sh[6] * __expf(sh[2] - M) + sh[7] * __expf(sh[3] - M);
    sh[8] = M;
    sh[9] = 1.0f / S2;
  }
  __syncthreads();
  float M = sh[8], rcp = sh[9];
  for (int i = tid; i < n4; i += 256) {
    float4 v = x4[i];
    v.x = __expf(v.x - M) * rcp;
    v.y = __expf(v.y - M) * rcp;
    v.z = __expf(v.z - M) * rcp;
    v.w = __expf(v.w - M) * rcp;
    x4[i] = v;
  }
}

}  // namespace

extern "C" void kernel_launch(void* const* d_in, const int* in_sizes, int n_in,
                              void* d_out, int out_size, void* d_ws, size_t ws_size,
                              hipStream_t stream) {
  const int*   src    = (const int*)d_in[0];
  const int*   trg    = (const int*)d_in[1];
  const float* emb_e  = (const float*)d_in[2];
  const float* emb_d  = (const float*)d_in[3];
  const float* qkv_e  = (const float*)d_in[4];
  const float* bqkv_e = (const float*)d_in[5];
  const float* wo_e   = (const float*)d_in[6];
  const float* bo_e   = (const float*)d_in[7];
  const float* qkv_m  = (const float*)d_in[8];
  const float* bqkv_m = (const float*)d_in[9];
  const float* wo_m   = (const float*)d_in[10];
  const float* bo_m   = (const float*)d_in[11];
  const float* qkv_c  = (const float*)d_in[12];
  const float* bqkv_c = (const float*)d_in[13];
  const float* wo_c   = (const float*)d_in[14];
  const float* bo_c   = (const float*)d_in[15];
  const float* gamma  = (const float*)d_in[16];
  const float* beta   = (const float*)d_in[17];
  const float* ffw1   = (const float*)d_in[18];
  const float* ffb1   = (const float*)d_in[19];
  const float* ffw2   = (const float*)d_in[20];
  const float* ffb2   = (const float*)d_in[21];
  const float* wout   = (const float*)d_in[22];
  const float* bout   = (const float*)d_in[23];
  float* out = (float*)d_out;

  float* w = (float*)d_ws;
  const size_t R = (size_t)kBS * kE;   // 2M elements
  // fp32 region (5R floats)
  float* enc_x = w + 0 * R;            // reused as n2d
  float* dec_x = w + 1 * R;            // reused as n3d
  float* t1    = w + 2 * R;
  float* n1    = w + 3 * R;            // reused as n1d
  float* n_enc = w + 4 * R;
  // bf16 region
  __hip_bfloat16* bb     = (__hip_bfloat16*)(w + 5 * R);
  __hip_bfloat16* enc_xb = bb;                       // R
  __hip_bfloat16* dec_xb = enc_xb + R;               // R
  __hip_bfloat16* n1b    = dec_xb + R;               // R
  __hip_bfloat16* n_encb = n1b + R;                  // R
  __hip_bfloat16* qkvb   = n_encb + R;               // 3R   [BS, 3HD]
  __hip_bfloat16* kvb    = qkvb + 3 * R;             // 2R   [BS, 2HD]
  __hip_bfloat16* qb1    = kvb + 2 * R;              // R    [BS, HD]
  __hip_bfloat16* vtb    = qb1 + R;                  // R    [B*H*64, S]
  __hip_bfloat16* ao16   = vtb + R;                  // R
  __hip_bfloat16* ffhb   = ao16 + R;                 // R/2
  __hip_bfloat16* Wqkv   = ffhb + R / 2;             // 1.5R  [3HD, E]
  __hip_bfloat16* Wo     = Wqkv + (size_t)3 * kHD * kE;  // [E rows of HD] via tcast
  __hip_bfloat16* Wf1 = Wo + (size_t)kE * kHD;       // [FH, E]
  __hip_bfloat16* Wf2 = Wf1 + (size_t)kFH * kE;      // [E, FH]
  __hip_bfloat16* Wv  = Wf2 + (size_t)kE * kFH;      // [V, E]
  float* pe = (float*)Wv;   // alias: PE table used before Wv is written

  auto tcast = [&](const float* s, __hip_bfloat16* d, int Rr, int Cc, int batch) {
    tcast_k<<<dim3(Cc / 32, Rr / 32, batch), 256, 0, stream>>>(s, d, Rr, Cc);
  };
  auto gemmb = [&](const __hip_bfloat16* A, const __hip_bfloat16* Bt, const float* bias,
                   void* C, int M, int N, int K, int mode) {
    int gridM = M / 128;
    gemm_bf16_k<<<dim3(gridM * (N / 128)), 256, 0, stream>>>(A, Bt, bias, C, N, K, mode, gridM);
  };
  auto vtrans = [&](const __hip_bfloat16* v, int sV) {
    vtrans_k<<<dim3(kS / 32, kD / 32, kB * kH), 256, 0, stream>>>(v, sV, vtb);
  };
  auto attn = [&](const __hip_bfloat16* q, int sQ, const __hip_bfloat16* k, int sK,
                  int causal) {
    attn_mfma_k<<<dim3(kS / 64, kH, kB), 256, 0, stream>>>(q, sQ, k, sK, vtb, ao16, causal);
  };
  auto ln = [&](const float* a, const float* b2, int sel, float* o1, __hip_bfloat16* o2) {
    ln_res_k<<<kBS, 256, 0, stream>>>(a, b2, gamma + sel * kE, beta + sel * kE, o1, o2);
  };

  pe_table_k<<<kS, 256, 0, stream>>>(pe);

  // ---------------- encoder ----------------
  embed_pe_k<<<kBS, 256, 0, stream>>>(src, emb_e, pe, enc_x, enc_xb);
  tcast(qkv_e, Wqkv, kE, kD, 3 * kH);
  tcast(wo_e, Wo, kHD, kE, 1);
  gemmb(enc_xb, Wqkv, bqkv_e, qkvb, kBS, 3 * kHD, kE, 2);
  vtrans(qkvb + 2 * kHD, 3 * kHD);
  attn(qkvb, 3 * kHD, qkvb + kHD, 3 * kHD, 0);
  gemmb(ao16, Wo, bo_e, t1, kBS, kE, kHD, 0);
  ln(enc_x, t1, 0, n1, n1b);
  tcast(ffw1, Wf1, kE, kFH, 1);
  tcast(ffw2, Wf2, kFH, kE, 1);
  gemmb(n1b, Wf1, ffb1, ffhb, kBS, kFH, kE, 3);
  gemmb(ffhb, Wf2, ffb2, t1, kBS, kE, kFH, 0);
  ln(n1, t1, 1, n_enc, n_encb);

  // ---------------- decoder ----------------
  embed_pe_k<<<kBS, 256, 0, stream>>>(trg, emb_d, pe, dec_x, dec_xb);
  tcast(qkv_m, Wqkv, kE, kD, 3 * kH);
  tcast(wo_m, Wo, kHD, kE, 1);
  gemmb(dec_xb, Wqkv, bqkv_m, qkvb, kBS, 3 * kHD, kE, 2);
  vtrans(qkvb + 2 * kHD, 3 * kHD);
  attn(qkvb, 3 * kHD, qkvb + kHD, 3 * kHD, 1);
  gemmb(ao16, Wo, bo_m, t1, kBS, kE, kHD, 0);
  ln(dec_x, t1, 2, n1, n1b);   // n1d

  tcast(qkv_c, Wqkv, kE, kD, 3 * kH);
  tcast(wo_c, Wo, kHD, kE, 1);
  gemmb(n1b, Wqkv, bqkv_c, qb1, kBS, kHD, kE, 2);
  gemmb(n_encb, Wqkv + (size_t)kHD * kE, bqkv_c + kHD, kvb, kBS, 2 * kHD, kE, 2);
  vtrans(kvb + kHD, 2 * kHD);
  attn(qb1, kHD, kvb, 2 * kHD, 0);
  gemmb(ao16, Wo, bo_c, t1, kBS, kE, kHD, 0);
  ln(n1, t1, 3, enc_x, enc_xb);  // n2d

  tcast(ffw1 + (size_t)kE * kFH, Wf1, kE, kFH, 1);
  tcast(ffw2 + (size_t)kFH * kE, Wf2, kFH, kE, 1);
  gemmb(enc_xb, Wf1, ffb1 + kFH, ffhb, kBS, kFH, kE, 3);
  gemmb(ffhb, Wf2, ffb2 + kE, t1, kBS, kE, kFH, 0);
  ln(enc_x, t1, 4, dec_x, dec_xb);  // n3d

  // ---------------- logits + softmax ----------------
  tcast(wout, Wv, kE, kV, 1);
  gemmb(dec_xb, Wv, bout, out, kBS, kV, kE, 0);
  softmax_rows_k<<<kBS, 256, 0, stream>>>(out);
}

// Round 5
// 764.866 us; speedup vs baseline: 13.0730x; 1.1641x over previous
//
#include <hip/hip_runtime.h>
#include <hip/hip_bf16.h>
#include <math.h>

namespace {

constexpr int kB = 2, kS = 1024, kE = 1024, kH = 16, kD = 64, kV = 32000, kFH = 512;
constexpr int kBS = kB * kS;   // 2048 rows
constexpr int kHD = kH * kD;   // 1024

typedef __attribute__((ext_vector_type(8))) short bf16x8;
typedef __attribute__((ext_vector_type(4))) float f32x4;

// ---------------- positional-encoding table: pe[s][e], s<kS ----------------
__global__ __launch_bounds__(256) void pe_table_k(float* __restrict__ pe) {
  int s = blockIdx.x;
  float* dst = pe + (size_t)s * kE;
  for (int e = threadIdx.x; e < kE; e += 256) {
    int i = e >> 1;
    float denom = powf(10000.0f, (float)(2 * i) * (1.0f / (float)kE));
    float ang = (float)s / denom;
    dst[e] = (e & 1) ? cosf(ang) : sinf(ang);
  }
}

// ---------------- embedding + PE (dual fp32/bf16 out) ----------------
__global__ __launch_bounds__(256) void embed_pe_k(const int* __restrict__ tok,
                                                  const float* __restrict__ emb,
                                                  const float* __restrict__ pe,
                                                  float* __restrict__ out,
                                                  __hip_bfloat16* __restrict__ outb) {
  int row = blockIdx.x;              // b*S + s
  int s = row & (kS - 1);
  int t = tok[row];
  const float4* src = (const float4*)(emb + (size_t)t * kE);
  const float4* per = (const float4*)(pe + (size_t)s * kE);
  float4* dst = (float4*)(out + (size_t)row * kE);
  __hip_bfloat16* dstb = outb + (size_t)row * kE;
  for (int e4 = threadIdx.x; e4 < kE / 4; e4 += 256) {
    float4 a = src[e4], p = per[e4];
    float4 v = make_float4(a.x + p.x, a.y + p.y, a.z + p.z, a.w + p.w);
    dst[e4] = v;
    union { __hip_bfloat16 h[4]; short4 s4; } u;
    u.h[0] = __float2bfloat16(v.x); u.h[1] = __float2bfloat16(v.y);
    u.h[2] = __float2bfloat16(v.z); u.h[3] = __float2bfloat16(v.w);
    ((short4*)dstb)[e4] = u.s4;
  }
}

// ---------------- transpose + cast: src[R,C] fp32 -> dst[C,R] bf16 (batched) -------
__global__ __launch_bounds__(256) void tcast_k(const float* __restrict__ src,
                                               __hip_bfloat16* __restrict__ dst,
                                               int R, int C) {
  __shared__ float tile[32][33];
  src += (size_t)blockIdx.z * R * C;
  dst += (size_t)blockIdx.z * R * C;
  int c0 = blockIdx.x * 32, r0 = blockIdx.y * 32;
  int tx = threadIdx.x & 31, ty = threadIdx.x >> 5;   // ty in 0..7
#pragma unroll
  for (int i = 0; i < 32; i += 8)
    tile[ty + i][tx] = src[(size_t)(r0 + ty + i) * C + c0 + tx];
  __syncthreads();
#pragma unroll
  for (int i = 0; i < 32; i += 8)
    dst[(size_t)(c0 + ty + i) * R + r0 + tx] = __float2bfloat16(tile[tx][ty + i]);
}

// ---------------- bf16 transpose per head: v[BS, sV] -> vt[(b*H+h)*64 + d][S] ------
__global__ __launch_bounds__(256) void vtrans_k(const __hip_bfloat16* __restrict__ v,
                                                int sV, __hip_bfloat16* __restrict__ vt) {
  __shared__ unsigned short tile[32][34];
  int s0 = blockIdx.x * 32, d0 = blockIdx.y * 32, bh = blockIdx.z;
  int b = bh >> 4, h = bh & 15;
  int tx = threadIdx.x & 31, ty = threadIdx.x >> 5;
  const unsigned short* src = (const unsigned short*)v;
  unsigned short* dst = (unsigned short*)vt;
#pragma unroll
  for (int i = 0; i < 32; i += 8)
    tile[ty + i][tx] = src[(size_t)(b * kS + s0 + ty + i) * sV + h * 64 + d0 + tx];
  __syncthreads();
#pragma unroll
  for (int i = 0; i < 32; i += 8)
    dst[(size_t)(bh * 64 + d0 + ty + i) * kS + s0 + tx] = tile[tx][ty + i];
}

// ---------------- bf16 MFMA GEMM (128x128 tile, m97 structure) ----------------
// mode: 0 = fp32 out, 1 = fp32+relu, 2 = bf16 out, 3 = bf16+relu
__global__ __launch_bounds__(256) void gemm_bf16_k(
    const __hip_bfloat16* __restrict__ A,   // [M,K] bf16
    const __hip_bfloat16* __restrict__ Bt,  // [N,K] bf16
    const float* __restrict__ bias,         // [N]
    void* __restrict__ Cout,
    int N, int K, int mode, int gridM) {
  __shared__ __align__(16) char As[128 * 64];   // [128 rows][32 bf16] = 8 KB
  __shared__ __align__(16) char Bs[128 * 64];
  const int nwg = gridDim.x;
  const int id = blockIdx.x;
  const int swz = (id & 7) * (nwg >> 3) + (id >> 3);
  const int bm = (swz % gridM) * 128;
  const int bn = (swz / gridM) * 128;
  const int tid = threadIdx.x;
  const int w = tid >> 6, lane = tid & 63;
  const int wr = w >> 1, wc = w & 1;
  const int lr = lane & 15, kg = lane >> 4;

  f32x4 acc[4][4] = {};

  for (int k0 = 0; k0 < K; k0 += 32) {
#pragma unroll
    for (int t = 0; t < 2; ++t) {
      int slot = (w * 2 + t) * 64 + lane;            // 0..511 (16B slots)
      int row = slot >> 2;
      int kc = (slot & 3) ^ ((row >> 1) & 3);        // inverse swizzle on source
      const __hip_bfloat16* ga = A + (size_t)(bm + row) * K + k0 + kc * 8;
      const __hip_bfloat16* gb = Bt + (size_t)(bn + row) * K + k0 + kc * 8;
      __builtin_amdgcn_global_load_lds(
          (const __attribute__((address_space(1))) void*)ga,
          (__attribute__((address_space(3))) void*)(As + (w * 2 + t) * 1024), 16, 0, 0);
      __builtin_amdgcn_global_load_lds(
          (const __attribute__((address_space(1))) void*)gb,
          (__attribute__((address_space(3))) void*)(Bs + (w * 2 + t) * 1024), 16, 0, 0);
    }
    __syncthreads();
    bf16x8 af[4], bfr[4];
#pragma unroll
    for (int i = 0; i < 4; ++i) {
      int row = wr * 64 + i * 16 + lr;
      af[i] = *(const bf16x8*)(As + row * 64 + ((kg ^ ((row >> 1) & 3)) << 4));
    }
#pragma unroll
    for (int j = 0; j < 4; ++j) {
      int row = wc * 64 + j * 16 + lr;
      bfr[j] = *(const bf16x8*)(Bs + row * 64 + ((kg ^ ((row >> 1) & 3)) << 4));
    }
#pragma unroll
    for (int i = 0; i < 4; ++i)
#pragma unroll
      for (int j = 0; j < 4; ++j)
        acc[i][j] = __builtin_amdgcn_mfma_f32_16x16x32_bf16(af[i], bfr[j], acc[i][j], 0, 0, 0);
    __syncthreads();
  }
  float* Cf = (float*)Cout;
  __hip_bfloat16* Cb = (__hip_bfloat16*)Cout;
#pragma unroll
  for (int j = 0; j < 4; ++j) {
    int col = bn + wc * 64 + j * 16 + lr;
    float bc = bias[col];
#pragma unroll
    for (int i = 0; i < 4; ++i) {
      int rbase = bm + wr * 64 + i * 16 + kg * 4;
#pragma unroll
      for (int r = 0; r < 4; ++r) {
        float val = acc[i][j][r] + bc;
        if (mode & 1) val = fmaxf(val, 0.0f);
        if (mode < 2) Cf[(size_t)(rbase + r) * N + col] = val;
        else          Cb[(size_t)(rbase + r) * N + col] = __float2bfloat16(val);
      }
    }
  }
}

// ---------------- 256x256 8-phase bf16 GEMM (vocab projection) ----------------
// 8 waves (2M x 4N), BK=64, 128 KB LDS (2 buffers x {A:256x64, B:256x64} bf16).
// Units per buffer: A0 rows 0-127, A1 rows 128-255, B0, B1 (16 KB each).
// Per K-tile: 4 phases x 16 MFMA; stages for tile t+1 issued at phases 0-1
// (into buffer freed after tile t-1); single vmcnt(0) at phase 3 end.
__global__ __launch_bounds__(512, 2) void gemm256_k(
    const __hip_bfloat16* __restrict__ A,   // [M,K]
    const __hip_bfloat16* __restrict__ Bt,  // [N,K]
    const float* __restrict__ bias,
    float* __restrict__ C,
    int N, int K, int gridM) {
  __shared__ __align__(16) char L[131072];
  const int tid = threadIdx.x, w = tid >> 6, lane = tid & 63;
  const int wm = w >> 2, wn = w & 3;
  const int lr = lane & 15, kg = lane >> 4;
  const int nwg = gridDim.x, id = blockIdx.x;
  const int swz = (id & 7) * (nwg >> 3) + (id >> 3);
  const int bm = (swz % gridM) * 256, bn = (swz / gridM) * 256;
  const int NT = K >> 6;

  const __hip_bfloat16* Ag = A + (size_t)bm * K;
  const __hip_bfloat16* Bg = Bt + (size_t)bn * K;

  // stage one 16KB unit (128 rows x 64 cols bf16), pre-swizzled source
  auto stage_unit = [&](int buf, int unit, const __hip_bfloat16* gbase, int ldk) {
#pragma unroll
    for (int j = 0; j < 2; ++j) {
      int Lb = w * 1024 + lane * 16 + j * 8192;   // byte offset within unit
      int row = Lb >> 7;
      int c = (Lb >> 4) & 7;
      int cs = c ^ (row & 7);
      const __hip_bfloat16* g = gbase + (size_t)row * ldk + cs * 8;
      __builtin_amdgcn_global_load_lds(
          (const __attribute__((address_space(1))) void*)g,
          (__attribute__((address_space(3))) void*)(L + buf * 65536 + unit * 16384 +
                                                    w * 1024 + j * 8192),
          16, 0, 0);
    }
  };

  f32x4 acc[8][4] = {};

  // prologue: stage tile 0 fully
  stage_unit(0, 0, Ag, K);
  stage_unit(0, 1, Ag + (size_t)128 * K, K);
  stage_unit(0, 2, Bg, K);
  stage_unit(0, 3, Bg + (size_t)128 * K, K);
  asm volatile("s_waitcnt vmcnt(0)" ::: "memory");
  __builtin_amdgcn_s_barrier();

  for (int t = 0; t < NT; ++t) {
    const int buf = t & 1, nxt = buf ^ 1;
    const char* Ab = L + buf * 65536 + wm * 16384;
    const char* Bb = L + buf * 65536 + 32768 + (wn >> 1) * 16384;
    const __hip_bfloat16* Agn = Ag + (t + 1) * 64;
    const __hip_bfloat16* Bgn = Bg + (t + 1) * 64;
    bf16x8 fB[4];
#pragma unroll
    for (int p = 0; p < 4; ++p) {
      const int kh = p >> 1, mbase = (p & 1) * 4;
      bf16x8 fA[4];
#pragma unroll
      for (int m = 0; m < 4; ++m) {
        int row = (mbase + m) * 16 + lr;
        fA[m] = *(const bf16x8*)(Ab + row * 128 + ((((kh << 2) | kg) ^ (lr & 7)) << 4));
      }
      if ((p & 1) == 0) {
#pragma unroll
        for (int n = 0; n < 4; ++n) {
          int row = ((wn & 1) << 6) + n * 16 + lr;
          fB[n] = *(const bf16x8*)(Bb + row * 128 + ((((kh << 2) | kg) ^ (lr & 7)) << 4));
        }
      }
      if (t + 1 < NT) {
        if (p == 0) {          // A-halves of t+1 (overwrite t-1, drained)
          stage_unit(nxt, 0, Agn, K);
          stage_unit(nxt, 1, Agn + (size_t)128 * K, K);
        } else if (p == 1) {   // B-halves of t+1
          stage_unit(nxt, 2, Bgn, K);
          stage_unit(nxt, 3, Bgn + (size_t)128 * K, K);
        }
      }
      __builtin_amdgcn_s_barrier();
      asm volatile("s_waitcnt lgkmcnt(0)" ::: "memory");
      __builtin_amdgcn_sched_barrier(0);
      __builtin_amdgcn_s_setprio(1);
#pragma unroll
      for (int m = 0; m < 4; ++m)
#pragma unroll
        for (int n = 0; n < 4; ++n)
          acc[mbase + m][n] =
              __builtin_amdgcn_mfma_f32_16x16x32_bf16(fA[m], fB[n], acc[mbase + m][n], 0, 0, 0);
      __builtin_amdgcn_s_setprio(0);
      __builtin_amdgcn_sched_barrier(0);
      if (p < 3) {
        __builtin_amdgcn_s_barrier();
      } else {
        asm volatile("s_waitcnt vmcnt(0)" ::: "memory");  // tile t+1 landed (all 8 loads)
        __builtin_amdgcn_s_barrier();
      }
    }
  }

  // epilogue
#pragma unroll
  for (int mg = 0; mg < 8; ++mg) {
    int rbase = bm + wm * 128 + mg * 16 + (kg << 2);
#pragma unroll
    for (int n = 0; n < 4; ++n) {
      int col = bn + (wn << 6) + n * 16 + lr;
      float bc = bias[col];
#pragma unroll
      for (int r = 0; r < 4; ++r)
        C[(size_t)(rbase + r) * N + col] = acc[mg][n][r] + bc;
    }
  }
}

// ---------------- MFMA flash attention ----------------
__global__ __launch_bounds__(256) void attn_mfma_k(
    const __hip_bfloat16* __restrict__ q, int sQ,
    const __hip_bfloat16* __restrict__ k, int sK,
    const __hip_bfloat16* __restrict__ vt,   // [(b*H+h)*64 + d][S]
    __hip_bfloat16* __restrict__ o,          // [BS][HD]
    int causal) {
  __shared__ __align__(16) char Ks[8192];
  __shared__ __align__(16) char Vs[8192];
  __shared__ __align__(16) char Ps[4][2304];   // per-wave P tile [16 q][72 bf16]
  const int tid = threadIdx.x, w = tid >> 6, l = tid & 63;
  const int lr = l & 15, lg = l >> 4;
  const int q0 = blockIdx.x * 64, h = blockIdx.y, b = blockIdx.z;

  const int qrow = q0 + w * 16 + lr;
  const __hip_bfloat16* qp = q + (size_t)(b * kS + qrow) * sQ + h * 64 + lg * 8;
  bf16x8 aQ0 = *(const bf16x8*)qp;
  bf16x8 aQ1 = *(const bf16x8*)(qp + 32);

  f32x4 oacc[4] = {};
  float mrun[4], lrun[4];
#pragma unroll
  for (int r = 0; r < 4; ++r) { mrun[r] = -INFINITY; lrun[r] = 0.0f; }

  const int ntiles = causal ? ((q0 >> 6) + 1) : (kS >> 6);
  const int diagT = causal ? (q0 >> 6) : -1;
  const char* kbase = (const char*)(k + (size_t)(b * kS) * sK + h * 64);
  const char* vbase = (const char*)(vt + (size_t)((b * kH + h) * 64) * kS);
  char* Pw = Ps[w];

  for (int t = 0; t < ntiles; ++t) {
    const int kv0 = t * 64;
    __syncthreads();
#pragma unroll
    for (int i = 0; i < 2; ++i) {
      int slot = w * 128 + i * 64 + l;
      int row = slot >> 3, sl = slot & 7, c = sl ^ (row & 7);
      const char* gk = kbase + (size_t)(kv0 + row) * sK * 2 + c * 16;
      const char* gv = vbase + (size_t)row * kS * 2 + kv0 * 2 + c * 16;
      __builtin_amdgcn_global_load_lds(
          (const __attribute__((address_space(1))) void*)gk,
          (__attribute__((address_space(3))) void*)(Ks + (w * 128 + i * 64) * 16), 16, 0, 0);
      __builtin_amdgcn_global_load_lds(
          (const __attribute__((address_space(1))) void*)gv,
          (__attribute__((address_space(3))) void*)(Vs + (w * 128 + i * 64) * 16), 16, 0, 0);
    }
    __syncthreads();

    // ---- S = Q @ K^T ----
    f32x4 sacc[4] = {};
#pragma unroll
    for (int nf = 0; nf < 4; ++nf) {
      int key = nf * 16 + lr;
#pragma unroll
      for (int kf = 0; kf < 2; ++kf) {
        int ch = (lg + kf * 4) ^ (key & 7);
        bf16x8 bK = *(const bf16x8*)(Ks + key * 128 + ch * 16);
        sacc[nf] = __builtin_amdgcn_mfma_f32_16x16x32_bf16(kf ? aQ1 : aQ0, bK, sacc[nf], 0, 0, 0);
      }
    }

    // ---- online softmax ----
#pragma unroll
    for (int r = 0; r < 4; ++r) {
      int row16 = lg * 4 + r;
      int qg = q0 + w * 16 + row16;
      float sv[4];
#pragma unroll
      for (int nf = 0; nf < 4; ++nf) {
        float s = sacc[nf][r] * 0.125f;
        if (t == diagT && (kv0 + nf * 16 + lr) > qg) s = -INFINITY;
        sv[nf] = s;
      }
      float mx = fmaxf(fmaxf(sv[0], sv[1]), fmaxf(sv[2], sv[3]));
#pragma unroll
      for (int m = 1; m < 16; m <<= 1) mx = fmaxf(mx, __shfl_xor(mx, m));
      float mnew = fmaxf(mrun[r], mx);
      float sc = __expf(mrun[r] - mnew);
      mrun[r] = mnew;
      float rs = 0.0f;
#pragma unroll
      for (int nf = 0; nf < 4; ++nf) {
        float p = __expf(sv[nf] - mnew);
        rs += p;
        *(__hip_bfloat16*)(Pw + row16 * 144 + (nf * 16 + lr) * 2) = __float2bfloat16(p);
      }
#pragma unroll
      for (int m = 1; m < 16; m <<= 1) rs += __shfl_xor(rs, m);
      lrun[r] = lrun[r] * sc + rs;
#pragma unroll
      for (int nfd = 0; nfd < 4; ++nfd) oacc[nfd][r] *= sc;
    }

    // ---- O += P @ V ----
    bf16x8 aP0 = *(const bf16x8*)(Pw + lr * 144 + (lg * 8) * 2);
    bf16x8 aP1 = *(const bf16x8*)(Pw + lr * 144 + (lg * 8 + 32) * 2);
#pragma unroll
    for (int nfd = 0; nfd < 4; ++nfd) {
      int d = nfd * 16 + lr;
#pragma unroll
      for (int kf = 0; kf < 2; ++kf) {
        int ch = (lg + kf * 4) ^ (d & 7);
        bf16x8 bV = *(const bf16x8*)(Vs + d * 128 + ch * 16);
        oacc[nfd] = __builtin_amdgcn_mfma_f32_16x16x32_bf16(kf ? aP1 : aP0, bV, oacc[nfd], 0, 0, 0);
      }
    }
  }

#pragma unroll
  for (int r = 0; r < 4; ++r) {
    float inv = 1.0f / lrun[r];
    int rowg = q0 + w * 16 + lg * 4 + r;
#pragma unroll
    for (int nfd = 0; nfd < 4; ++nfd)
      o[(size_t)(b * kS + rowg) * kHD + h * 64 + nfd * 16 + lr] =
          __float2bfloat16(oacc[nfd][r] * inv);
  }
}

// ---------------- residual + LayerNorm (dual fp32/bf16 out) ----------------
__global__ __launch_bounds__(256) void ln_res_k(const float* __restrict__ a,
                                                const float* __restrict__ b,
                                                const float* __restrict__ gamma,
                                                const float* __restrict__ beta,
                                                float* __restrict__ out,
                                                __hip_bfloat16* __restrict__ outb) {
  __shared__ float sh[10];
  int row = blockIdx.x;
  const float* ar = a + (size_t)row * kE;
  const float* br = b + (size_t)row * kE;
  int tid = threadIdx.x;
  float t[4], s = 0.0f, q2 = 0.0f;
#pragma unroll
  for (int i = 0; i < 4; ++i) {
    int e = tid + i * 256;
    t[i] = ar[e] + br[e];
    s += t[i];
    q2 += t[i] * t[i];
  }
  for (int o = 32; o > 0; o >>= 1) { s += __shfl_down(s, o); q2 += __shfl_down(q2, o); }
  int lane = tid & 63, wid = tid >> 6;
  if (lane == 0) { sh[wid] = s; sh[4 + wid] = q2; }
  __syncthreads();
  if (tid == 0) {
    float S2 = sh[0] + sh[1] + sh[2] + sh[3];
    float Q2 = sh[4] + sh[5] + sh[6] + sh[7];
    float mean = S2 * (1.0f / kE);
    float var = Q2 * (1.0f / kE) - mean * mean;
    sh[8] = mean;
    sh[9] = rsqrtf(var + 1e-15f);
  }
  __syncthreads();
  float mean = sh[8], inv = sh[9];
#pragma unroll
  for (int i = 0; i < 4; ++i) {
    int e = tid + i * 256;
    float v = gamma[e] * ((t[i] - mean) * inv) + beta[e];
    out[(size_t)row * kE + e] = v;
    outb[(size_t)row * kE + e] = __float2bfloat16(v);
  }
}

// ---------------- row softmax over V (in place, register-resident single pass) -----
__global__ __launch_bounds__(512) void softmax_rows_k(float* __restrict__ x) {
  __shared__ float sh[18];
  int row = blockIdx.x;
  float4* x4 = (float4*)(x + (size_t)row * kV);
  const int n4 = kV / 4;   // 8000
  int tid = threadIdx.x;
  float4 v[16];
  float m = -INFINITY, sum = 0.0f;
#pragma unroll
  for (int i = 0; i < 16; ++i) {
    int idx = tid + i * 512;
    if (idx < n4) {
      v[i] = x4[idx];
      float mx = fmaxf(fmaxf(v[i].x, v[i].y), fmaxf(v[i].z, v[i].w));
      float nm = fmaxf(m, mx);
      sum = sum * __expf(m - nm) + __expf(v[i].x - nm) + __expf(v[i].y - nm) +
            __expf(v[i].z - nm) + __expf(v[i].w - nm);
      m = nm;
    }
  }
  for (int o = 32; o > 0; o >>= 1) {
    float om = __shfl_down(m, o), os = __shfl_down(sum, o);
    float nm = fmaxf(m, om);
    sum = sum * __expf(m - nm) + os * __expf(om - nm);
    m = nm;
  }
  int lane = tid & 63, wid = tid >> 6;
  if (lane == 0) { sh[wid] = m; sh[8 + wid] = sum; }
  __syncthreads();
  if (tid == 0) {
    float M = sh[0], S2 = 0.0f;
#pragma unroll
    for (int i2 = 1; i2 < 8; ++i2) M = fmaxf(M, sh[i2]);
#pragma unroll
    for (int i2 = 0; i2 < 8; ++i2) S2 += sh[8 + i2] * __expf(sh[i2] - M);
    sh[16] = M;
    sh[17] = 1.0f / S2;
  }
  __syncthreads();
  float M = sh[16], rcp = sh[17];
#pragma unroll
  for (int i = 0; i < 16; ++i) {
    int idx = tid + i * 512;
    if (idx < n4) {
      float4 o2;
      o2.x = __expf(v[i].x - M) * rcp;
      o2.y = __expf(v[i].y - M) * rcp;
      o2.z = __expf(v[i].z - M) * rcp;
      o2.w = __expf(v[i].w - M) * rcp;
      x4[idx] = o2;
    }
  }
}

}  // namespace

extern "C" void kernel_launch(void* const* d_in, const int* in_sizes, int n_in,
                              void* d_out, int out_size, void* d_ws, size_t ws_size,
                              hipStream_t stream) {
  const int*   src    = (const int*)d_in[0];
  const int*   trg    = (const int*)d_in[1];
  const float* emb_e  = (const float*)d_in[2];
  const float* emb_d  = (const float*)d_in[3];
  const float* qkv_e  = (const float*)d_in[4];
  const float* bqkv_e = (const float*)d_in[5];
  const float* wo_e   = (const float*)d_in[6];
  const float* bo_e   = (const float*)d_in[7];
  const float* qkv_m  = (const float*)d_in[8];
  const float* bqkv_m = (const float*)d_in[9];
  const float* wo_m   = (const float*)d_in[10];
  const float* bo_m   = (const float*)d_in[11];
  const float* qkv_c  = (const float*)d_in[12];
  const float* bqkv_c = (const float*)d_in[13];
  const float* wo_c   = (const float*)d_in[14];
  const float* bo_c   = (const float*)d_in[15];
  const float* gamma  = (const float*)d_in[16];
  const float* beta   = (const float*)d_in[17];
  const float* ffw1   = (const float*)d_in[18];
  const float* ffb1   = (const float*)d_in[19];
  const float* ffw2   = (const float*)d_in[20];
  const float* ffb2   = (const float*)d_in[21];
  const float* wout   = (const float*)d_in[22];
  const float* bout   = (const float*)d_in[23];
  float* out = (float*)d_out;

  float* w = (float*)d_ws;
  const size_t R = (size_t)kBS * kE;   // 2M elements
  float* enc_x = w + 0 * R;            // reused as n2d
  float* dec_x = w + 1 * R;            // reused as n3d
  float* t1    = w + 2 * R;
  float* n1    = w + 3 * R;            // reused as n1d
  float* n_enc = w + 4 * R;
  __hip_bfloat16* bb     = (__hip_bfloat16*)(w + 5 * R);
  __hip_bfloat16* enc_xb = bb;                       // R
  __hip_bfloat16* dec_xb = enc_xb + R;               // R
  __hip_bfloat16* n1b    = dec_xb + R;               // R
  __hip_bfloat16* n_encb = n1b + R;                  // R
  __hip_bfloat16* qkvb   = n_encb + R;               // 3R   [BS, 3HD]
  __hip_bfloat16* kvb    = qkvb + 3 * R;             // 2R   [BS, 2HD]
  __hip_bfloat16* qb1    = kvb + 2 * R;              // R    [BS, HD]
  __hip_bfloat16* vtb    = qb1 + R;                  // R    [B*H*64, S]
  __hip_bfloat16* ao16   = vtb + R;                  // R
  __hip_bfloat16* ffhb   = ao16 + R;                 // R/2
  __hip_bfloat16* Wqkv   = ffhb + R / 2;             // 1.5R  [3HD, E]
  __hip_bfloat16* Wo     = Wqkv + (size_t)3 * kHD * kE;
  __hip_bfloat16* Wf1 = Wo + (size_t)kE * kHD;       // [FH, E]
  __hip_bfloat16* Wf2 = Wf1 + (size_t)kFH * kE;      // [E, FH]
  __hip_bfloat16* Wv  = Wf2 + (size_t)kE * kFH;      // [V, E]
  float* pe = (float*)Wv;   // alias: PE table used before Wv is written

  auto tcast = [&](const float* s, __hip_bfloat16* d, int Rr, int Cc, int batch) {
    tcast_k<<<dim3(Cc / 32, Rr / 32, batch), 256, 0, stream>>>(s, d, Rr, Cc);
  };
  auto gemmb = [&](const __hip_bfloat16* A, const __hip_bfloat16* Bt, const float* bias,
                   void* C, int M, int N, int K, int mode) {
    int gridM = M / 128;
    gemm_bf16_k<<<dim3(gridM * (N / 128)), 256, 0, stream>>>(A, Bt, bias, C, N, K, mode, gridM);
  };
  auto vtrans = [&](const __hip_bfloat16* v, int sV) {
    vtrans_k<<<dim3(kS / 32, kD / 32, kB * kH), 256, 0, stream>>>(v, sV, vtb);
  };
  auto attn = [&](const __hip_bfloat16* q, int sQ, const __hip_bfloat16* k, int sK,
                  int causal) {
    attn_mfma_k<<<dim3(kS / 64, kH, kB), 256, 0, stream>>>(q, sQ, k, sK, vtb, ao16, causal);
  };
  auto ln = [&](const float* a, const float* b2, int sel, float* o1, __hip_bfloat16* o2) {
    ln_res_k<<<kBS, 256, 0, stream>>>(a, b2, gamma + sel * kE, beta + sel * kE, o1, o2);
  };

  pe_table_k<<<kS, 256, 0, stream>>>(pe);

  // ---------------- encoder ----------------
  embed_pe_k<<<kBS, 256, 0, stream>>>(src, emb_e, pe, enc_x, enc_xb);
  tcast(qkv_e, Wqkv, kE, kD, 3 * kH);
  tcast(wo_e, Wo, kHD, kE, 1);
  gemmb(enc_xb, Wqkv, bqkv_e, qkvb, kBS, 3 * kHD, kE, 2);
  vtrans(qkvb + 2 * kHD, 3 * kHD);
  attn(qkvb, 3 * kHD, qkvb + kHD, 3 * kHD, 0);
  gemmb(ao16, Wo, bo_e, t1, kBS, kE, kHD, 0);
  ln(enc_x, t1, 0, n1, n1b);
  tcast(ffw1, Wf1, kE, kFH, 1);
  tcast(ffw2, Wf2, kFH, kE, 1);
  gemmb(n1b, Wf1, ffb1, ffhb, kBS, kFH, kE, 3);
  gemmb(ffhb, Wf2, ffb2, t1, kBS, kE, kFH, 0);
  ln(n1, t1, 1, n_enc, n_encb);

  // ---------------- decoder ----------------
  embed_pe_k<<<kBS, 256, 0, stream>>>(trg, emb_d, pe, dec_x, dec_xb);
  tcast(qkv_m, Wqkv, kE, kD, 3 * kH);
  tcast(wo_m, Wo, kHD, kE, 1);
  gemmb(dec_xb, Wqkv, bqkv_m, qkvb, kBS, 3 * kHD, kE, 2);
  vtrans(qkvb + 2 * kHD, 3 * kHD);
  attn(qkvb, 3 * kHD, qkvb + kHD, 3 * kHD, 1);
  gemmb(ao16, Wo, bo_m, t1, kBS, kE, kHD, 0);
  ln(dec_x, t1, 2, n1, n1b);   // n1d

  tcast(qkv_c, Wqkv, kE, kD, 3 * kH);
  tcast(wo_c, Wo, kHD, kE, 1);
  gemmb(n1b, Wqkv, bqkv_c, qb1, kBS, kHD, kE, 2);
  gemmb(n_encb, Wqkv + (size_t)kHD * kE, bqkv_c + kHD, kvb, kBS, 2 * kHD, kE, 2);
  vtrans(kvb + kHD, 2 * kHD);
  attn(qb1, kHD, kvb, 2 * kHD, 0);
  gemmb(ao16, Wo, bo_c, t1, kBS, kE, kHD, 0);
  ln(n1, t1, 3, enc_x, enc_xb);  // n2d

  tcast(ffw1 + (size_t)kE * kFH, Wf1, kE, kFH, 1);
  tcast(ffw2 + (size_t)kFH * kE, Wf2, kFH, kE, 1);
  gemmb(enc_xb, Wf1, ffb1 + kFH, ffhb, kBS, kFH, kE, 3);
  gemmb(ffhb, Wf2, ffb2 + kE, t1, kBS, kE, kFH, 0);
  ln(enc_x, t1, 4, dec_x, dec_xb);  // n3d

  // ---------------- logits (8-phase 256^2 GEMM) + softmax ----------------
  tcast(wout, Wv, kE, kV, 1);
  gemm256_k<<<dim3((kBS / 256) * (kV / 256)), 512, 0, stream>>>(
      dec_xb, Wv, bout, out, kV, kE, kBS / 256);
  softmax_rows_k<<<kBS, 512, 0, stream>>>(out);
}

// Round 6
// 695.105 us; speedup vs baseline: 14.3850x; 1.1004x over previous
//
#include <hip/hip_runtime.h>
#include <hip/hip_bf16.h>
#include <math.h>

namespace {

constexpr int kB = 2, kS = 1024, kE = 1024, kH = 16, kD = 64, kV = 32000, kFH = 512;
constexpr int kBS = kB * kS;   // 2048 rows
constexpr int kHD = kH * kD;   // 1024

typedef __attribute__((ext_vector_type(8))) short bf16x8;
typedef __attribute__((ext_vector_type(4))) float f32x4;

#define GLDS(g, l) __builtin_amdgcn_global_load_lds(                          \
      (const __attribute__((address_space(1))) void*)(g),                     \
      (__attribute__((address_space(3))) void*)(l), 16, 0, 0)

// ---------------- positional-encoding table: pe[s][e], s<kS ----------------
__global__ __launch_bounds__(256) void pe_table_k(float* __restrict__ pe) {
  int s = blockIdx.x;
  float* dst = pe + (size_t)s * kE;
  for (int e = threadIdx.x; e < kE; e += 256) {
    int i = e >> 1;
    float denom = powf(10000.0f, (float)(2 * i) * (1.0f / (float)kE));
    float ang = (float)s / denom;
    dst[e] = (e & 1) ? cosf(ang) : sinf(ang);
  }
}

// ---------------- embedding + PE (dual fp32/bf16 out) ----------------
__global__ __launch_bounds__(256) void embed_pe_k(const int* __restrict__ tok,
                                                  const float* __restrict__ emb,
                                                  const float* __restrict__ pe,
                                                  float* __restrict__ out,
                                                  __hip_bfloat16* __restrict__ outb) {
  int row = blockIdx.x;              // b*S + s
  int s = row & (kS - 1);
  int t = tok[row];
  const float4* src = (const float4*)(emb + (size_t)t * kE);
  const float4* per = (const float4*)(pe + (size_t)s * kE);
  float4* dst = (float4*)(out + (size_t)row * kE);
  __hip_bfloat16* dstb = outb + (size_t)row * kE;
  for (int e4 = threadIdx.x; e4 < kE / 4; e4 += 256) {
    float4 a = src[e4], p = per[e4];
    float4 v = make_float4(a.x + p.x, a.y + p.y, a.z + p.z, a.w + p.w);
    dst[e4] = v;
    union { __hip_bfloat16 h[4]; short4 s4; } u;
    u.h[0] = __float2bfloat16(v.x); u.h[1] = __float2bfloat16(v.y);
    u.h[2] = __float2bfloat16(v.z); u.h[3] = __float2bfloat16(v.w);
    ((short4*)dstb)[e4] = u.s4;
  }
}

// ---------------- transpose + cast: src[R,C] fp32 -> dst[C,R] bf16 (batched) -------
__global__ __launch_bounds__(256) void tcast_k(const float* __restrict__ src,
                                               __hip_bfloat16* __restrict__ dst,
                                               int R, int C) {
  __shared__ float tile[32][33];
  src += (size_t)blockIdx.z * R * C;
  dst += (size_t)blockIdx.z * R * C;
  int c0 = blockIdx.x * 32, r0 = blockIdx.y * 32;
  int tx = threadIdx.x & 31, ty = threadIdx.x >> 5;   // ty in 0..7
#pragma unroll
  for (int i = 0; i < 32; i += 8)
    tile[ty + i][tx] = src[(size_t)(r0 + ty + i) * C + c0 + tx];
  __syncthreads();
#pragma unroll
  for (int i = 0; i < 32; i += 8)
    dst[(size_t)(c0 + ty + i) * R + r0 + tx] = __float2bfloat16(tile[tx][ty + i]);
}

// ---------------- bf16 transpose per head: v[BS, sV] -> vt[(b*H+h)*64 + d][S] ------
__global__ __launch_bounds__(256) void vtrans_k(const __hip_bfloat16* __restrict__ v,
                                                int sV, __hip_bfloat16* __restrict__ vt) {
  __shared__ unsigned short tile[32][34];
  int s0 = blockIdx.x * 32, d0 = blockIdx.y * 32, bh = blockIdx.z;
  int b = bh >> 4, h = bh & 15;
  int tx = threadIdx.x & 31, ty = threadIdx.x >> 5;
  const unsigned short* src = (const unsigned short*)v;
  unsigned short* dst = (unsigned short*)vt;
#pragma unroll
  for (int i = 0; i < 32; i += 8)
    tile[ty + i][tx] = src[(size_t)(b * kS + s0 + ty + i) * sV + h * 64 + d0 + tx];
  __syncthreads();
#pragma unroll
  for (int i = 0; i < 32; i += 8)
    dst[(size_t)(bh * 64 + d0 + ty + i) * kS + s0 + tx] = tile[tx][ty + i];
}

// ---------------- 128x128 bf16 GEMM, 3-buffer BK=32 counted-vmcnt pipeline ---------
// mode: 0 = fp32 out, 1 = fp32+relu, 2 = bf16 out, 3 = bf16+relu
__global__ __launch_bounds__(256) void gemm_bf16_k(
    const __hip_bfloat16* __restrict__ A,   // [M,K] bf16
    const __hip_bfloat16* __restrict__ Bt,  // [N,K] bf16
    const float* __restrict__ bias,         // [N]
    void* __restrict__ Cout,
    int N, int K, int mode, int gridM) {
  __shared__ __align__(16) char L[3][16384];   // per buf: A 8KB | B 8KB
  const int nwg = gridDim.x, id = blockIdx.x;
  const int swz = (id & 7) * (nwg >> 3) + (id >> 3);
  const int bm = (swz % gridM) * 128, bn = (swz / gridM) * 128;
  const int tid = threadIdx.x, w = tid >> 6, lane = tid & 63;
  const int wr = w >> 1, wc = w & 1;
  const int lr = lane & 15, kg = lane >> 4;
  const int NT = K >> 5;
  const __hip_bfloat16* Ag = A + (size_t)bm * K;
  const __hip_bfloat16* Bg = Bt + (size_t)bn * K;

  auto stage = [&](int t) {   // 4 loads/thread (A 2 + B 2)
    const int buf = t % 3, k0 = t * 32;
#pragma unroll
    for (int j = 0; j < 2; ++j) {
      int slot = w * 64 + lane + j * 256;          // 0..511 (16B slots)
      int row = slot >> 2;
      int cs = (slot & 3) ^ ((row >> 1) & 3);      // inverse swizzle on source
      GLDS(Ag + (size_t)row * K + k0 + cs * 8, L[buf] + w * 1024 + j * 4096);
      GLDS(Bg + (size_t)row * K + k0 + cs * 8, L[buf] + 8192 + w * 1024 + j * 4096);
    }
  };

  f32x4 acc[4][4] = {};
  stage(0);
  stage(1);
  asm volatile("s_waitcnt vmcnt(4)" ::: "memory");
  __builtin_amdgcn_s_barrier();

  for (int t = 0; t < NT; ++t) {
    const char* buf = L[t % 3];
    if (t + 2 < NT) stage(t + 2);
    bf16x8 af[4], bfr[4];
#pragma unroll
    for (int i = 0; i < 4; ++i) {
      int row = wr * 64 + i * 16 + lr;
      af[i] = *(const bf16x8*)(buf + row * 64 + ((kg ^ ((row >> 1) & 3)) << 4));
    }
#pragma unroll
    for (int j = 0; j < 4; ++j) {
      int row = wc * 64 + j * 16 + lr;
      bfr[j] = *(const bf16x8*)(buf + 8192 + row * 64 + ((kg ^ ((row >> 1) & 3)) << 4));
    }
    __builtin_amdgcn_s_setprio(1);
#pragma unroll
    for (int i = 0; i < 4; ++i)
#pragma unroll
      for (int j = 0; j < 4; ++j)
        acc[i][j] = __builtin_amdgcn_mfma_f32_16x16x32_bf16(af[i], bfr[j], acc[i][j], 0, 0, 0);
    __builtin_amdgcn_s_setprio(0);
    if (t + 2 < NT)
      asm volatile("s_waitcnt vmcnt(4) lgkmcnt(0)" ::: "memory");
    else
      asm volatile("s_waitcnt vmcnt(0) lgkmcnt(0)" ::: "memory");
    __builtin_amdgcn_s_barrier();
  }

  float* Cf = (float*)Cout;
  __hip_bfloat16* Cb = (__hip_bfloat16*)Cout;
#pragma unroll
  for (int j = 0; j < 4; ++j) {
    int col = bn + wc * 64 + j * 16 + lr;
    float bc = bias[col];
#pragma unroll
    for (int i = 0; i < 4; ++i) {
      int rbase = bm + wr * 64 + i * 16 + kg * 4;
#pragma unroll
      for (int r = 0; r < 4; ++r) {
        float val = acc[i][j][r] + bc;
        if (mode & 1) val = fmaxf(val, 0.0f);
        if (mode < 2) Cf[(size_t)(rbase + r) * N + col] = val;
        else          Cb[(size_t)(rbase + r) * N + col] = __float2bfloat16(val);
      }
    }
  }
}

// ---------------- 256x256 bf16 GEMM, 3-buffer BK=32 counted-vmcnt (vocab) ----------
__global__ __launch_bounds__(512, 2) void gemm256_k(
    const __hip_bfloat16* __restrict__ A,   // [M,K]
    const __hip_bfloat16* __restrict__ Bt,  // [N,K]
    const float* __restrict__ bias,
    float* __restrict__ C,
    int N, int K, int gridM) {
  __shared__ __align__(16) char L[3][32768];   // per buf: A 16KB | B 16KB
  const int tid = threadIdx.x, w = tid >> 6, lane = tid & 63;
  const int wm = w >> 2, wn = w & 3;
  const int lr = lane & 15, kg = lane >> 4;
  const int nwg = gridDim.x, id = blockIdx.x;
  const int swz = (id & 7) * (nwg >> 3) + (id >> 3);
  const int bm = (swz % gridM) * 256, bn = (swz / gridM) * 256;
  const int NT = K >> 5;
  const __hip_bfloat16* Ag = A + (size_t)bm * K;
  const __hip_bfloat16* Bg = Bt + (size_t)bn * K;

  auto stage = [&](int t) {   // 4 loads/thread (A 2 + B 2)
    const int buf = t % 3, k0 = t * 32;
#pragma unroll
    for (int j = 0; j < 2; ++j) {
      int slot = w * 64 + lane + j * 512;          // 0..1023 (16B slots)
      int row = slot >> 2;                         // 0..255
      int cs = (slot & 3) ^ ((row >> 1) & 3);
      GLDS(Ag + (size_t)row * K + k0 + cs * 8, L[buf] + w * 1024 + j * 8192);
      GLDS(Bg + (size_t)row * K + k0 + cs * 8, L[buf] + 16384 + w * 1024 + j * 8192);
    }
  };

  f32x4 acc[8][4] = {};
  stage(0);
  stage(1);
  asm volatile("s_waitcnt vmcnt(4)" ::: "memory");
  __builtin_amdgcn_s_barrier();

  for (int t = 0; t < NT; ++t) {
    const char* buf = L[t % 3];
    if (t + 2 < NT) stage(t + 2);
    bf16x8 af[8], bfr[4];
#pragma unroll
    for (int mg = 0; mg < 8; ++mg) {
      int row = wm * 128 + mg * 16 + lr;
      af[mg] = *(const bf16x8*)(buf + row * 64 + ((kg ^ ((row >> 1) & 3)) << 4));
    }
#pragma unroll
    for (int n = 0; n < 4; ++n) {
      int row = wn * 64 + n * 16 + lr;
      bfr[n] = *(const bf16x8*)(buf + 16384 + row * 64 + ((kg ^ ((row >> 1) & 3)) << 4));
    }
    __builtin_amdgcn_s_setprio(1);
#pragma unroll
    for (int mg = 0; mg < 8; ++mg)
#pragma unroll
      for (int n = 0; n < 4; ++n)
        acc[mg][n] = __builtin_amdgcn_mfma_f32_16x16x32_bf16(af[mg], bfr[n], acc[mg][n], 0, 0, 0);
    __builtin_amdgcn_s_setprio(0);
    if (t + 2 < NT)
      asm volatile("s_waitcnt vmcnt(4) lgkmcnt(0)" ::: "memory");
    else
      asm volatile("s_waitcnt vmcnt(0) lgkmcnt(0)" ::: "memory");
    __builtin_amdgcn_s_barrier();
  }

  // epilogue
#pragma unroll
  for (int mg = 0; mg < 8; ++mg) {
    int rbase = bm + wm * 128 + mg * 16 + (kg << 2);
#pragma unroll
    for (int n = 0; n < 4; ++n) {
      int col = bn + (wn << 6) + n * 16 + lr;
      float bc = bias[col];
#pragma unroll
      for (int r = 0; r < 4; ++r)
        C[(size_t)(rbase + r) * N + col] = acc[mg][n][r] + bc;
    }
  }
}

// ---------------- MFMA flash attention ----------------
__global__ __launch_bounds__(256) void attn_mfma_k(
    const __hip_bfloat16* __restrict__ q, int sQ,
    const __hip_bfloat16* __restrict__ k, int sK,
    const __hip_bfloat16* __restrict__ vt,   // [(b*H+h)*64 + d][S]
    __hip_bfloat16* __restrict__ o,          // [BS][HD]
    int causal) {
  __shared__ __align__(16) char Ks[8192];
  __shared__ __align__(16) char Vs[8192];
  __shared__ __align__(16) char Ps[4][2304];   // per-wave P tile [16 q][72 bf16]
  const int tid = threadIdx.x, w = tid >> 6, l = tid & 63;
  const int lr = l & 15, lg = l >> 4;
  const int q0 = blockIdx.x * 64, h = blockIdx.y, b = blockIdx.z;

  const int qrow = q0 + w * 16 + lr;
  const __hip_bfloat16* qp = q + (size_t)(b * kS + qrow) * sQ + h * 64 + lg * 8;
  bf16x8 aQ0 = *(const bf16x8*)qp;
  bf16x8 aQ1 = *(const bf16x8*)(qp + 32);

  f32x4 oacc[4] = {};
  float mrun[4], lrun[4];
#pragma unroll
  for (int r = 0; r < 4; ++r) { mrun[r] = -INFINITY; lrun[r] = 0.0f; }

  const int ntiles = causal ? ((q0 >> 6) + 1) : (kS >> 6);
  const int diagT = causal ? (q0 >> 6) : -1;
  const char* kbase = (const char*)(k + (size_t)(b * kS) * sK + h * 64);
  const char* vbase = (const char*)(vt + (size_t)((b * kH + h) * 64) * kS);
  char* Pw = Ps[w];

  for (int t = 0; t < ntiles; ++t) {
    const int kv0 = t * 64;
    __syncthreads();
#pragma unroll
    for (int i = 0; i < 2; ++i) {
      int slot = w * 128 + i * 64 + l;
      int row = slot >> 3, sl = slot & 7, c = sl ^ (row & 7);
      const char* gk = kbase + (size_t)(kv0 + row) * sK * 2 + c * 16;
      const char* gv = vbase + (size_t)row * kS * 2 + kv0 * 2 + c * 16;
      GLDS(gk, Ks + (w * 128 + i * 64) * 16);
      GLDS(gv, Vs + (w * 128 + i * 64) * 16);
    }
    __syncthreads();

    // ---- S = Q @ K^T ----
    f32x4 sacc[4] = {};
#pragma unroll
    for (int nf = 0; nf < 4; ++nf) {
      int key = nf * 16 + lr;
#pragma unroll
      for (int kf = 0; kf < 2; ++kf) {
        int ch = (lg + kf * 4) ^ (key & 7);
        bf16x8 bK = *(const bf16x8*)(Ks + key * 128 + ch * 16);
        sacc[nf] = __builtin_amdgcn_mfma_f32_16x16x32_bf16(kf ? aQ1 : aQ0, bK, sacc[nf], 0, 0, 0);
      }
    }

    // ---- online softmax ----
#pragma unroll
    for (int r = 0; r < 4; ++r) {
      int row16 = lg * 4 + r;
      int qg = q0 + w * 16 + row16;
      float sv[4];
#pragma unroll
      for (int nf = 0; nf < 4; ++nf) {
        float s = sacc[nf][r] * 0.125f;
        if (t == diagT && (kv0 + nf * 16 + lr) > qg) s = -INFINITY;
        sv[nf] = s;
      }
      float mx = fmaxf(fmaxf(sv[0], sv[1]), fmaxf(sv[2], sv[3]));
#pragma unroll
      for (int m = 1; m < 16; m <<= 1) mx = fmaxf(mx, __shfl_xor(mx, m));
      float mnew = fmaxf(mrun[r], mx);
      float sc = __expf(mrun[r] - mnew);
      mrun[r] = mnew;
      float rs = 0.0f;
#pragma unroll
      for (int nf = 0; nf < 4; ++nf) {
        float p = __expf(sv[nf] - mnew);
        rs += p;
        *(__hip_bfloat16*)(Pw + row16 * 144 + (nf * 16 + lr) * 2) = __float2bfloat16(p);
      }
#pragma unroll
      for (int m = 1; m < 16; m <<= 1) rs += __shfl_xor(rs, m);
      lrun[r] = lrun[r] * sc + rs;
#pragma unroll
      for (int nfd = 0; nfd < 4; ++nfd) oacc[nfd][r] *= sc;
    }

    // ---- O += P @ V ----
    bf16x8 aP0 = *(const bf16x8*)(Pw + lr * 144 + (lg * 8) * 2);
    bf16x8 aP1 = *(const bf16x8*)(Pw + lr * 144 + (lg * 8 + 32) * 2);
#pragma unroll
    for (int nfd = 0; nfd < 4; ++nfd) {
      int d = nfd * 16 + lr;
#pragma unroll
      for (int kf = 0; kf < 2; ++kf) {
        int ch = (lg + kf * 4) ^ (d & 7);
        bf16x8 bV = *(const bf16x8*)(Vs + d * 128 + ch * 16);
        oacc[nfd] = __builtin_amdgcn_mfma_f32_16x16x32_bf16(kf ? aP1 : aP0, bV, oacc[nfd], 0, 0, 0);
      }
    }
  }

#pragma unroll
  for (int r = 0; r < 4; ++r) {
    float inv = 1.0f / lrun[r];
    int rowg = q0 + w * 16 + lg * 4 + r;
#pragma unroll
    for (int nfd = 0; nfd < 4; ++nfd)
      o[(size_t)(b * kS + rowg) * kHD + h * 64 + nfd * 16 + lr] =
          __float2bfloat16(oacc[nfd][r] * inv);
  }
}

// ---------------- residual + LayerNorm (dual fp32/bf16 out, float4) ----------------
__global__ __launch_bounds__(256) void ln_res_k(const float* __restrict__ a,
                                                const float* __restrict__ b,
                                                const float* __restrict__ gamma,
                                                const float* __restrict__ beta,
                                                float* __restrict__ out,
                                                __hip_bfloat16* __restrict__ outb) {
  __shared__ float sh[10];
  int row = blockIdx.x, tid = threadIdx.x;
  const float4* a4 = (const float4*)(a + (size_t)row * kE);
  const float4* b4 = (const float4*)(b + (size_t)row * kE);
  float4 t = a4[tid], u = b4[tid];
  t.x += u.x; t.y += u.y; t.z += u.z; t.w += u.w;
  float s = t.x + t.y + t.z + t.w;
  float q2 = t.x * t.x + t.y * t.y + t.z * t.z + t.w * t.w;
  for (int o = 32; o > 0; o >>= 1) { s += __shfl_down(s, o); q2 += __shfl_down(q2, o); }
  int lane = tid & 63, wid = tid >> 6;
  if (lane == 0) { sh[wid] = s; sh[4 + wid] = q2; }
  __syncthreads();
  if (tid == 0) {
    float S2 = sh[0] + sh[1] + sh[2] + sh[3];
    float Q2 = sh[4] + sh[5] + sh[6] + sh[7];
    float mean = S2 * (1.0f / kE);
    float var = Q2 * (1.0f / kE) - mean * mean;
    sh[8] = mean;
    sh[9] = rsqrtf(var + 1e-15f);
  }
  __syncthreads();
  float mean = sh[8], inv = sh[9];
  float4 g = ((const float4*)gamma)[tid], be = ((const float4*)beta)[tid];
  float4 v;
  v.x = g.x * ((t.x - mean) * inv) + be.x;
  v.y = g.y * ((t.y - mean) * inv) + be.y;
  v.z = g.z * ((t.z - mean) * inv) + be.z;
  v.w = g.w * ((t.w - mean) * inv) + be.w;
  ((float4*)(out + (size_t)row * kE))[tid] = v;
  union { __hip_bfloat16 h[4]; short4 s4; } uo;
  uo.h[0] = __float2bfloat16(v.x); uo.h[1] = __float2bfloat16(v.y);
  uo.h[2] = __float2bfloat16(v.z); uo.h[3] = __float2bfloat16(v.w);
  ((short4*)(outb + (size_t)row * kE))[tid] = uo.s4;
}

// ---------------- row softmax over V (in place, register-resident single pass) -----
__global__ __launch_bounds__(512) void softmax_rows_k(float* __restrict__ x) {
  __shared__ float sh[18];
  int row = blockIdx.x;
  float4* x4 = (float4*)(x + (size_t)row * kV);
  const int n4 = kV / 4;   // 8000
  int tid = threadIdx.x;
  float4 v[16];
  float m = -INFINITY, sum = 0.0f;
#pragma unroll
  for (int i = 0; i < 16; ++i) {
    int idx = tid + i * 512;
    if (idx < n4) {
      v[i] = x4[idx];
      float mx = fmaxf(fmaxf(v[i].x, v[i].y), fmaxf(v[i].z, v[i].w));
      float nm = fmaxf(m, mx);
      sum = sum * __expf(m - nm) + __expf(v[i].x - nm) + __expf(v[i].y - nm) +
            __expf(v[i].z - nm) + __expf(v[i].w - nm);
      m = nm;
    }
  }
  for (int o = 32; o > 0; o >>= 1) {
    float om = __shfl_down(m, o), os = __shfl_down(sum, o);
    float nm = fmaxf(m, om);
    sum = sum * __expf(m - nm) + os * __expf(om - nm);
    m = nm;
  }
  int lane = tid & 63, wid = tid >> 6;
  if (lane == 0) { sh[wid] = m; sh[8 + wid] = sum; }
  __syncthreads();
  if (tid == 0) {
    float M = sh[0], S2 = 0.0f;
#pragma unroll
    for (int i2 = 1; i2 < 8; ++i2) M = fmaxf(M, sh[i2]);
#pragma unroll
    for (int i2 = 0; i2 < 8; ++i2) S2 += sh[8 + i2] * __expf(sh[i2] - M);
    sh[16] = M;
    sh[17] = 1.0f / S2;
  }
  __syncthreads();
  float M = sh[16], rcp = sh[17];
#pragma unroll
  for (int i = 0; i < 16; ++i) {
    int idx = tid + i * 512;
    if (idx < n4) {
      float4 o2;
      o2.x = __expf(v[i].x - M) * rcp;
      o2.y = __expf(v[i].y - M) * rcp;
      o2.z = __expf(v[i].z - M) * rcp;
      o2.w = __expf(v[i].w - M) * rcp;
      x4[idx] = o2;
    }
  }
}

}  // namespace

extern "C" void kernel_launch(void* const* d_in, const int* in_sizes, int n_in,
                              void* d_out, int out_size, void* d_ws, size_t ws_size,
                              hipStream_t stream) {
  const int*   src    = (const int*)d_in[0];
  const int*   trg    = (const int*)d_in[1];
  const float* emb_e  = (const float*)d_in[2];
  const float* emb_d  = (const float*)d_in[3];
  const float* qkv_e  = (const float*)d_in[4];
  const float* bqkv_e = (const float*)d_in[5];
  const float* wo_e   = (const float*)d_in[6];
  const float* bo_e   = (const float*)d_in[7];
  const float* qkv_m  = (const float*)d_in[8];
  const float* bqkv_m = (const float*)d_in[9];
  const float* wo_m   = (const float*)d_in[10];
  const float* bo_m   = (const float*)d_in[11];
  const float* qkv_c  = (const float*)d_in[12];
  const float* bqkv_c = (const float*)d_in[13];
  const float* wo_c   = (const float*)d_in[14];
  const float* bo_c   = (const float*)d_in[15];
  const float* gamma  = (const float*)d_in[16];
  const float* beta   = (const float*)d_in[17];
  const float* ffw1   = (const float*)d_in[18];
  const float* ffb1   = (const float*)d_in[19];
  const float* ffw2   = (const float*)d_in[20];
  const float* ffb2   = (const float*)d_in[21];
  const float* wout   = (const float*)d_in[22];
  const float* bout   = (const float*)d_in[23];
  float* out = (float*)d_out;

  float* w = (float*)d_ws;
  const size_t R = (size_t)kBS * kE;   // 2M elements
  float* enc_x = w + 0 * R;            // reused as n2d
  float* dec_x = w + 1 * R;            // reused as n3d
  float* t1    = w + 2 * R;
  float* n1    = w + 3 * R;            // reused as n1d
  float* n_enc = w + 4 * R;
  __hip_bfloat16* bb     = (__hip_bfloat16*)(w + 5 * R);
  __hip_bfloat16* enc_xb = bb;                       // R
  __hip_bfloat16* dec_xb = enc_xb + R;               // R
  __hip_bfloat16* n1b    = dec_xb + R;               // R
  __hip_bfloat16* n_encb = n1b + R;                  // R
  __hip_bfloat16* qkvb   = n_encb + R;               // 3R   [BS, 3HD]
  __hip_bfloat16* kvb    = qkvb + 3 * R;             // 2R   [BS, 2HD]
  __hip_bfloat16* qb1    = kvb + 2 * R;              // R    [BS, HD]
  __hip_bfloat16* vtb    = qb1 + R;                  // R    [B*H*64, S]
  __hip_bfloat16* ao16   = vtb + R;                  // R
  __hip_bfloat16* ffhb   = ao16 + R;                 // R/2
  __hip_bfloat16* Wqkv   = ffhb + R / 2;             // 1.5R  [3HD, E]
  __hip_bfloat16* Wo     = Wqkv + (size_t)3 * kHD * kE;
  __hip_bfloat16* Wf1 = Wo + (size_t)kE * kHD;       // [FH, E]
  __hip_bfloat16* Wf2 = Wf1 + (size_t)kFH * kE;      // [E, FH]
  __hip_bfloat16* Wv  = Wf2 + (size_t)kE * kFH;      // [V, E]
  float* pe = (float*)Wv;   // alias: PE table used before Wv is written

  auto tcast = [&](const float* s, __hip_bfloat16* d, int Rr, int Cc, int batch) {
    tcast_k<<<dim3(Cc / 32, Rr / 32, batch), 256, 0, stream>>>(s, d, Rr, Cc);
  };
  auto gemmb = [&](const __hip_bfloat16* A, const __hip_bfloat16* Bt, const float* bias,
                   void* C, int M, int N, int K, int mode) {
    int gridM = M / 128;
    gemm_bf16_k<<<dim3(gridM * (N / 128)), 256, 0, stream>>>(A, Bt, bias, C, N, K, mode, gridM);
  };
  auto vtrans = [&](const __hip_bfloat16* v, int sV) {
    vtrans_k<<<dim3(kS / 32, kD / 32, kB * kH), 256, 0, stream>>>(v, sV, vtb);
  };
  auto attn = [&](const __hip_bfloat16* q, int sQ, const __hip_bfloat16* k, int sK,
                  int causal) {
    attn_mfma_k<<<dim3(kS / 64, kH, kB), 256, 0, stream>>>(q, sQ, k, sK, vtb, ao16, causal);
  };
  auto ln = [&](const float* a, const float* b2, int sel, float* o1, __hip_bfloat16* o2) {
    ln_res_k<<<kBS, 256, 0, stream>>>(a, b2, gamma + sel * kE, beta + sel * kE, o1, o2);
  };

  pe_table_k<<<kS, 256, 0, stream>>>(pe);

  // ---------------- encoder ----------------
  embed_pe_k<<<kBS, 256, 0, stream>>>(src, emb_e, pe, enc_x, enc_xb);
  tcast(qkv_e, Wqkv, kE, kD, 3 * kH);
  tcast(wo_e, Wo, kHD, kE, 1);
  gemmb(enc_xb, Wqkv, bqkv_e, qkvb, kBS, 3 * kHD, kE, 2);
  vtrans(qkvb + 2 * kHD, 3 * kHD);
  attn(qkvb, 3 * kHD, qkvb + kHD, 3 * kHD, 0);
  gemmb(ao16, Wo, bo_e, t1, kBS, kE, kHD, 0);
  ln(enc_x, t1, 0, n1, n1b);
  tcast(ffw1, Wf1, kE, kFH, 1);
  tcast(ffw2, Wf2, kFH, kE, 1);
  gemmb(n1b, Wf1, ffb1, ffhb, kBS, kFH, kE, 3);
  gemmb(ffhb, Wf2, ffb2, t1, kBS, kE, kFH, 0);
  ln(n1, t1, 1, n_enc, n_encb);

  // ---------------- decoder ----------------
  embed_pe_k<<<kBS, 256, 0, stream>>>(trg, emb_d, pe, dec_x, dec_xb);
  tcast(qkv_m, Wqkv, kE, kD, 3 * kH);
  tcast(wo_m, Wo, kHD, kE, 1);
  gemmb(dec_xb, Wqkv, bqkv_m, qkvb, kBS, 3 * kHD, kE, 2);
  vtrans(qkvb + 2 * kHD, 3 * kHD);
  attn(qkvb, 3 * kHD, qkvb + kHD, 3 * kHD, 1);
  gemmb(ao16, Wo, bo_m, t1, kBS, kE, kHD, 0);
  ln(dec_x, t1, 2, n1, n1b);   // n1d

  tcast(qkv_c, Wqkv, kE, kD, 3 * kH);
  tcast(wo_c, Wo, kHD, kE, 1);
  gemmb(n1b, Wqkv, bqkv_c, qb1, kBS, kHD, kE, 2);
  gemmb(n_encb, Wqkv + (size_t)kHD * kE, bqkv_c + kHD, kvb, kBS, 2 * kHD, kE, 2);
  vtrans(kvb + kHD, 2 * kHD);
  attn(qb1, kHD, kvb, 2 * kHD, 0);
  gemmb(ao16, Wo, bo_c, t1, kBS, kE, kHD, 0);
  ln(n1, t1, 3, enc_x, enc_xb);  // n2d

  tcast(ffw1 + (size_t)kE * kFH, Wf1, kE, kFH, 1);
  tcast(ffw2 + (size_t)kFH * kE, Wf2, kFH, kE, 1);
  gemmb(enc_xb, Wf1, ffb1 + kFH, ffhb, kBS, kFH, kE, 3);
  gemmb(ffhb, Wf2, ffb2 + kE, t1, kBS, kE, kFH, 0);
  ln(enc_x, t1, 4, dec_x, dec_xb);  // n3d

  // ---------------- logits (256^2 pipelined GEMM) + softmax ----------------
  tcast(wout, Wv, kE, kV, 1);
  gemm256_k<<<dim3((kBS / 256) * (kV / 256)), 512, 0, stream>>>(
      dec_xb, Wv, bout, out, kV, kE, kBS / 256);
  softmax_rows_k<<<kBS, 512, 0, stream>>>(out);
}